// Round 7
// baseline (421.509 us; speedup 1.0000x reference)
//
#include <hip/hip_runtime.h>
#include <hip/hip_bf16.h>
#include <cstdint>
#include <cstddef>

// Problem constants
#define HW   512
#define HW2  1024
#define SZ   (512 * 512)
#define NPT  (34 * 34)   // 1156 warped 1024-res points per 16x16 output tile
#define K_PTS 5          // ceil(1156 / 256)
#define SRCW 36          // staged source window: 36x36
#define NSRC (SRCW * SRCW)   // 1296
#define MARG 9           // window origin = tile_origin - MARG
#define FDIM 18          // staged field window: rows/cols [t0-1, t0+16]
#define NFLD (FDIM * FDIM)   // 324

// jax.image.resize bilinear upsample 512->1024 taps for output index i (0..1023)
struct UpTap { int i0, i1; float w0, w1; };

__device__ __forceinline__ UpTap up_tap(int i) {
  UpTap t;
  int k = i >> 1;
  if ((i & 1) == 0) {
    t.i0 = k - 1; t.i1 = k; t.w0 = 0.25f; t.w1 = 0.75f;
    if (k == 0) { t.i0 = 0; t.w0 = 0.0f; t.w1 = 1.0f; }
  } else {
    t.i0 = k; t.i1 = k + 1; t.w0 = 0.75f; t.w1 = 0.25f;
    if (k == HW - 1) { t.i1 = HW - 1; t.w0 = 1.0f; t.w1 = 0.0f; }
  }
  return t;
}

// Both warp-field components, bilinear-upsampled, served from the staged LDS tile.
__device__ __forceinline__ float2 up_at2(const float2* __restrict__ f,
                                         int yi, int xi, int oy, int ox) {
  UpTap ty = up_tap(yi), tx = up_tap(xi);
  const float2* r0 = f + (ty.i0 - oy) * FDIM - ox;
  const float2* r1 = f + (ty.i1 - oy) * FDIM - ox;
  float2 v00 = r0[tx.i0], v01 = r0[tx.i1];
  float2 v10 = r1[tx.i0], v11 = r1[tx.i1];
  float2 r;
  r.x = ty.w0 * (tx.w0 * v00.x + tx.w1 * v01.x) + ty.w1 * (tx.w0 * v10.x + tx.w1 * v11.x);
  r.y = ty.w0 * (tx.w0 * v00.y + tx.w1 * v01.y) + ty.w1 * (tx.w0 * v10.y + tx.w1 * v11.y);
  return r;
}

// Separable decomposition of (warp-bilinear in 1024-space) o (2x upsample):
// a 3-tap stencil on the 512 grid. Base clamped to [0,509]; out-of-range
// corners get weight 0 (zero padding, mask pre-clamp).
__device__ __forceinline__ void axis_taps(float s, int& base, float& w0, float& w1, float& w2) {
  float f0 = floorf(s);
  int i0 = (int)f0;
  float fr = s - f0;
  int b = (i0 & 1) ? (i0 >> 1) : (i0 >> 1) - 1;
  b = b < 0 ? 0 : (b > (HW - 3) ? (HW - 3) : b);
  float w[3] = {0.0f, 0.0f, 0.0f};
  if ((unsigned)i0 < (unsigned)HW2) {
    UpTap t = up_tap(i0);
    w[t.i0 - b] += (1.0f - fr) * t.w0;
    w[t.i1 - b] += (1.0f - fr) * t.w1;
  }
  if ((unsigned)(i0 + 1) < (unsigned)HW2) {
    UpTap t = up_tap(i0 + 1);
    w[t.i0 - b] += fr * t.w0;
    w[t.i1 - b] += fr * t.w1;
  }
  base = b; w0 = w[0]; w1 = w[1]; w2 = w[2];
}

// Per-point separable 3x3 stencil. locoff >= 0: index into staged 36x36 LDS window.
// locoff < 0: rare fallback, ~locoff = global by*HW+bx offset (displacement > ~8px).
struct PtTaps {
  int   locoff;
  float wy0, wy1, wy2, wx0, wx1, wx2;
};

// Stage the 18x18 field window (fx,fy interleaved) into LDS.
__device__ __forceinline__ void stage_field(const float* __restrict__ fx,
                                            const float* __restrict__ fy,
                                            float2* __restrict__ sf,
                                            int fy0, int fx0, int tid) {
  #pragma unroll
  for (int i = 0; i < 2; ++i) {
    int p = tid + i * 256;
    if (p < NFLD) {
      int r = p / FDIM, c = p % FDIM;
      int gy = fy0 + r; gy = gy < 0 ? 0 : (gy > HW - 1 ? HW - 1 : gy);
      int gx = fx0 + c; gx = gx < 0 ? 0 : (gx > HW - 1 ? HW - 1 : gx);
      size_t o = (size_t)gy * HW + gx;
      sf[p] = make_float2(fx[o], fy[o]);
    }
  }
}

// Taps from the LDS-staged field (no global loads).
__device__ __forceinline__ void compute_taps(const float2* __restrict__ sf,
                                             int fy0, int fx0,
                                             int gx0, int gy0, int xo, int yo, int tid,
                                             PtTaps (&pt)[K_PTS]) {
  #pragma unroll
  for (int i = 0; i < K_PTS; ++i) {
    int p = tid + i * 256;
    pt[i].locoff = 0;
    pt[i].wy0 = pt[i].wy1 = pt[i].wy2 = 0.0f;
    pt[i].wx0 = pt[i].wx1 = pt[i].wx2 = 0.0f;
    if (p < NPT) {
      int ry = p / 34, rx = p % 34;
      int yy = gy0 + ry, xx = gx0 + rx;
      if ((unsigned)yy < (unsigned)HW2 && (unsigned)xx < (unsigned)HW2) {
        float2 d = up_at2(sf, yy, xx, fy0, fx0);
        float sx = (float)xx + 2.0f * d.x;
        float sy = (float)yy + 2.0f * d.y;
        int bx, by;
        axis_taps(sx, bx, pt[i].wx0, pt[i].wx1, pt[i].wx2);
        axis_taps(sy, by, pt[i].wy0, pt[i].wy1, pt[i].wy2);
        int rx_ = bx - xo, ry_ = by - yo;
        if ((unsigned)rx_ <= (unsigned)(SRCW - 3) && (unsigned)ry_ <= (unsigned)(SRCW - 3))
          pt[i].locoff = ry_ * SRCW + rx_;          // in staged window
        else
          pt[i].locoff = ~(by * HW + bx);           // fallback: global offset
      }
    }
  }
}

// Stage a channel pair's 36x36 source window into LDS (float2 interleaved).
__device__ __forceinline__ void stage_pair(const float* __restrict__ p0,
                                           const float* __restrict__ p1,
                                           float2* __restrict__ s_src,
                                           int xo, int yo, int tid) {
  #pragma unroll
  for (int i = 0; i < 6; ++i) {                   // 6*256 = 1536 >= 1296
    int p = tid + i * 256;
    if (p < NSRC) {
      int r = p / SRCW, c = p % SRCW;
      int gy = yo + r; gy = gy < 0 ? 0 : (gy > HW - 1 ? HW - 1 : gy);
      int gx = xo + c; gx = gx < 0 ? 0 : (gx > HW - 1 ? HW - 1 : gx);
      size_t o = (size_t)gy * HW + gx;
      s_src[p] = make_float2(p0[o], p1[o]);
    }
  }
}

__device__ __forceinline__ float eval3_global(const float* __restrict__ pl, int off, const PtTaps& t) {
  const float* p0 = pl + off;
  float r0 = t.wx0 * p0[0]        + t.wx1 * p0[1]          + t.wx2 * p0[2];
  float r1 = t.wx0 * p0[HW]       + t.wx1 * p0[HW + 1]     + t.wx2 * p0[HW + 2];
  float r2 = t.wx0 * p0[2 * HW]   + t.wx1 * p0[2 * HW + 1] + t.wx2 * p0[2 * HW + 2];
  return t.wy0 * r0 + t.wy1 * r1 + t.wy2 * r2;
}

// Evaluate all points of a channel pair from the staged LDS window into s_tile.
__device__ __forceinline__ void eval_round(const float2* __restrict__ s_src,
                                           float2* __restrict__ s_tile,
                                           const float* __restrict__ plane0,
                                           const float* __restrict__ plane1,
                                           const PtTaps (&pt)[K_PTS], int tid) {
  #pragma unroll
  for (int i = 0; i < K_PTS; ++i) {
    int p = tid + i * 256;
    if (p < NPT) {
      const PtTaps t = pt[i];
      float a0, a1;
      if (t.locoff >= 0) {
        const float2* s = s_src + t.locoff;
        float2 v00 = s[0],        v01 = s[1],            v02 = s[2];
        float2 v10 = s[SRCW],     v11 = s[SRCW + 1],     v12 = s[SRCW + 2];
        float2 v20 = s[2 * SRCW], v21 = s[2 * SRCW + 1], v22 = s[2 * SRCW + 2];
        float r00 = t.wx0 * v00.x + t.wx1 * v01.x + t.wx2 * v02.x;
        float r10 = t.wx0 * v10.x + t.wx1 * v11.x + t.wx2 * v12.x;
        float r20 = t.wx0 * v20.x + t.wx1 * v21.x + t.wx2 * v22.x;
        float r01 = t.wx0 * v00.y + t.wx1 * v01.y + t.wx2 * v02.y;
        float r11 = t.wx0 * v10.y + t.wx1 * v11.y + t.wx2 * v12.y;
        float r21 = t.wx0 * v20.y + t.wx1 * v21.y + t.wx2 * v22.y;
        a0 = t.wy0 * r00 + t.wy1 * r10 + t.wy2 * r20;
        a1 = t.wy0 * r01 + t.wy1 * r11 + t.wy2 * r21;
      } else {                                     // ~never taken (|disp| > ~8px)
        int off = ~t.locoff;
        a0 = eval3_global(plane0, off, t);
        a1 = eval3_global(plane1, off, t);
      }
      s_tile[p] = make_float2(a0, a1);
    }
  }
}

// -------------------- K1/K4: res_warp_img(tgt, res_field, rollback=1) --------------------
// Round-1 structure (VGPR=64 invariant) + LDS-staged warp field for the tap phase.
__global__ void warp_img_kernel(const float* __restrict__ x,    // [B,32,512,512]
                                const float* __restrict__ res,  // [B,2,512,512]
                                float* __restrict__ out)        // [B,32,512,512]
{
  __shared__ float2 s_src[NSRC];   // 10368 B
  __shared__ float2 s_tile[NPT];   //  9248 B  (prologue: holds the 18x18 field tile)

  const int b = blockIdx.z;
  const int tx0 = blockIdx.x * 16, ty0 = blockIdx.y * 16;
  const int gx0 = tx0 * 2 - 1, gy0 = ty0 * 2 - 1;
  const int xo = tx0 - MARG, yo = ty0 - MARG;
  const int fy0 = ty0 - 1, fx0 = tx0 - 1;
  const int tid = threadIdx.x;

  const float* resx = res + (size_t)b * 2 * SZ;
  const float* resy = resx + SZ;
  const float* tgt  = x + ((size_t)b * 32 + 16) * SZ;

  // Issue round-0 channel staging + field staging together.
  stage_pair(tgt, tgt + SZ, s_src, xo, yo, tid);
  stage_field(resx, resy, s_tile, fy0, fx0, tid);

  // Downsample stencil weights for this thread's output pixel
  const int ly = tid >> 4, lx = tid & 15;
  const int oy = ty0 + ly, ox = tx0 + lx;
  const float RW[4] = {0.25f, 0.75f, 0.75f, 0.25f};
  float wy[4], wx[4];
  float sumy = 0.f, sumx = 0.f;
  #pragma unroll
  for (int d = 0; d < 4; ++d) {
    int g = 2 * oy - 1 + d;
    wy[d] = ((unsigned)g < (unsigned)HW2) ? RW[d] : 0.0f; sumy += wy[d];
    g = 2 * ox - 1 + d;
    wx[d] = ((unsigned)g < (unsigned)HW2) ? RW[d] : 0.0f; sumx += wx[d];
  }
  const float inv = 1.0f / (sumy * sumx);

  __syncthreads();                                 // field + round-0 src ready

  PtTaps pt[K_PTS];
  compute_taps(s_tile, fy0, fx0, gx0, gy0, xo, yo, tid, pt);

  __syncthreads();                                 // field reads done; s_tile free

  for (int c = 0; c < 16; c += 2) {
    const float* plane0 = tgt + (size_t)c * SZ;
    eval_round(s_src, s_tile, plane0, plane0 + SZ, pt, tid);
    __syncthreads();                               // s_tile ready; s_src free

    if (c < 14)                                    // overlap next staging with phase 3
      stage_pair(plane0 + 2 * SZ, plane0 + 3 * SZ, s_src, xo, yo, tid);

    float acc0 = 0.0f, acc1 = 0.0f;
    #pragma unroll
    for (int dy = 0; dy < 4; ++dy) {
      float r0 = 0.0f, r1 = 0.0f;
      const int base = (2 * ly + dy) * 34 + 2 * lx;
      #pragma unroll
      for (int dx = 0; dx < 4; ++dx) {
        float2 v = s_tile[base + dx];
        r0 += wx[dx] * v.x;
        r1 += wx[dx] * v.y;
      }
      acc0 += wy[dy] * r0;
      acc1 += wy[dy] * r1;
    }
    size_t o = (((size_t)b * 32 + 16 + c) * HW + oy) * HW + ox;
    out[o] = acc0 * inv;
    out[o + SZ] = acc1 * inv;
    __syncthreads();                               // s_src(next) ready; s_tile free
  }
}

// -------------------- K2: 3x3 conv over 50-ch bundle -> 2-ch adj --------------------
// LDS-pipe overhaul: (1) weights read straight from global Wc with wave-uniform
// indices -> scalar s_load path, removing 900 LDS broadcast reads/thread;
// (2) halo staged as 4-plane-interleaved float4 -> 9 ds_read_b128 per quad
// instead of 36 ds_read_b32. Double-buffered quads, T14 write-late prefetch.
// Fused src passthrough (out ch 0..15 = halo center taps) kept from round 5.
#define CHN 18                     // halo width (16 + 2)
#define CHE (CHN * CHN)            // 324 elements

__global__ void __launch_bounds__(256)
conv_kernel(const float* __restrict__ x,
            const float* __restrict__ res,
            const float* __restrict__ Wc,      // [2,50,3,3]
            const float* __restrict__ bc,      // [2]
            float* __restrict__ out,           // [B,32,512,512]: reads ch16..31 (warped), writes ch0..15
            float* __restrict__ adj)           // [B,2,512,512]
{
  __shared__ float4 sh[2][CHE];    // two quad-buffers, 4 planes interleaved: 10368 B

  const int tid = threadIdx.x;
  const int b = blockIdx.z;
  const int tx0 = blockIdx.x * 16, ty0 = blockIdx.y * 16;
  const int ty = tid >> 4, tx = tid & 15;

  const float* px = x + (size_t)b * 32 * SZ;
  const float* pw = out + ((size_t)b * 32 + 16) * SZ;
  const float* pr = res + (size_t)b * 2 * SZ;

  // Halo-slot addressing (identical for every plane; computed once)
  const int ry0 = tid / CHN, rx0 = tid - ry0 * CHN;
  const int hy0 = ty0 - 1 + ry0, hx0 = tx0 - 1 + rx0;
  const bool ok0 = (unsigned)hy0 < (unsigned)HW && (unsigned)hx0 < (unsigned)HW;
  const int off0 = hy0 * HW + hx0;               // only deref'd under ok0
  const int p1 = tid + 256;
  const bool sl1 = p1 < CHE;                     // tid < 68
  const int ry1 = p1 / CHN, rx1 = p1 - ry1 * CHN;
  const int hy1 = ty0 - 1 + ry1, hx1 = tx0 - 1 + rx1;
  const bool ok1 = sl1 && (unsigned)hy1 < (unsigned)HW && (unsigned)hx1 < (unsigned)HW;
  const int off1 = hy1 * HW + hx1;

  #define PLANE(ic) ((ic) < 32 ? px + (size_t)(ic) * SZ \
                   : (ic) < 48 ? pw + (size_t)((ic) - 32) * SZ \
                   : pr + (size_t)((ic) - 48) * SZ)

  float acc0 = bc[0];
  float acc1 = bc[1];

  float4 q0, q1;
  {  // prologue: stage quad 0 (planes 0..3) into sh[0]
    q0 = make_float4(0.f, 0.f, 0.f, 0.f);
    q1 = make_float4(0.f, 0.f, 0.f, 0.f);
    if (ok0) q0 = make_float4(PLANE(0)[off0], PLANE(1)[off0], PLANE(2)[off0], PLANE(3)[off0]);
    if (ok1) q1 = make_float4(PLANE(0)[off1], PLANE(1)[off1], PLANE(2)[off1], PLANE(3)[off1]);
    sh[0][tid] = q0;
    if (sl1) sh[0][p1] = q1;
  }

  const size_t pix = (size_t)(ty0 + ty) * HW + (tx0 + tx);

  for (int kk = 0; kk < 12; ++kk) {
    __syncthreads();                      // current quad ready; other buffer free
    // issue next stage's loads before compute (T14 split)
    q0 = make_float4(0.f, 0.f, 0.f, 0.f);
    q1 = make_float4(0.f, 0.f, 0.f, 0.f);
    if (kk < 11) {
      const int ic = 4 * kk + 4;
      if (ok0) q0 = make_float4(PLANE(ic)[off0], PLANE(ic + 1)[off0], PLANE(ic + 2)[off0], PLANE(ic + 3)[off0]);
      if (ok1) q1 = make_float4(PLANE(ic)[off1], PLANE(ic + 1)[off1], PLANE(ic + 2)[off1], PLANE(ic + 3)[off1]);
    } else {                              // final: the res pair (ch 48,49)
      if (ok0) { q0.x = PLANE(48)[off0]; q0.y = PLANE(49)[off0]; }
      if (ok1) { q1.x = PLANE(48)[off1]; q1.y = PLANE(49)[off1]; }
    }

    const float4* hp = sh[kk & 1];
    const float* w0 = Wc + (size_t)(4 * kk) * 9;         // uniform -> s_load
    const float* w1 = Wc + 450 + (size_t)(4 * kk) * 9;
    float4 cen;
    #pragma unroll
    for (int ky = 0; ky < 3; ++ky) {
      #pragma unroll
      for (int kx = 0; kx < 3; ++kx) {
        const int widx = ky * 3 + kx;
        float4 v = hp[(ty + ky) * CHN + tx + kx];
        if (ky == 1 && kx == 1) cen = v;
        acc0 += v.x * w0[widx];
        acc0 += v.y * w0[9 + widx];
        acc0 += v.z * w0[18 + widx];
        acc0 += v.w * w0[27 + widx];
        acc1 += v.x * w1[widx];
        acc1 += v.y * w1[9 + widx];
        acc1 += v.z * w1[18 + widx];
        acc1 += v.w * w1[27 + widx];
      }
    }

    if (kk < 4) {                         // fused K0: out ch 4kk..4kk+3 = x ch 4kk..4kk+3
      out[((size_t)b * 32 + 4 * kk + 0) * SZ + pix] = cen.x;
      out[((size_t)b * 32 + 4 * kk + 1) * SZ + pix] = cen.y;
      out[((size_t)b * 32 + 4 * kk + 2) * SZ + pix] = cen.z;
      out[((size_t)b * 32 + 4 * kk + 3) * SZ + pix] = cen.w;
    }

    float4* sd = sh[(kk & 1) ^ 1];        // write-late into the other buffer
    sd[tid] = q0;
    if (sl1) sd[p1] = q1;
  }

  // epilogue: res pair sits in sh[0] (kk=11 wrote into sh[(11&1)^1] = sh[0])
  __syncthreads();
  {
    const float4* hp = sh[0];
    const float* w0 = Wc + (size_t)48 * 9;
    const float* w1 = Wc + 450 + (size_t)48 * 9;
    #pragma unroll
    for (int ky = 0; ky < 3; ++ky) {
      #pragma unroll
      for (int kx = 0; kx < 3; ++kx) {
        const int widx = ky * 3 + kx;
        float4 v = hp[(ty + ky) * CHN + tx + kx];
        acc0 += v.x * w0[widx];
        acc0 += v.y * w0[9 + widx];
        acc1 += v.x * w1[widx];
        acc1 += v.y * w1[9 + widx];
      }
    }
  }
  #undef PLANE

  adj[((size_t)b * 2 + 0) * SZ + pix] = acc0;
  adj[((size_t)b * 2 + 1) * SZ + pix] = acc1;
}

// -------------------- K3: new_res = adj + downsample(warp(up(res), 2*up(adj))) --------------------
// (the reference's *2 on the warped field values and the *0.5 after downsample cancel exactly)
__global__ void new_res_kernel(const float* __restrict__ res,  // [B,2,512,512]
                               const float* __restrict__ adj,  // [B,2,512,512]
                               float* __restrict__ nres)       // [B,2,512,512]
{
  __shared__ float2 s_src[NSRC];
  __shared__ float2 s_tile[NPT];

  const int b = blockIdx.z;
  const int tx0 = blockIdx.x * 16, ty0 = blockIdx.y * 16;
  const int gx0 = tx0 * 2 - 1, gy0 = ty0 * 2 - 1;
  const int xo = tx0 - MARG, yo = ty0 - MARG;
  const int fy0 = ty0 - 1, fx0 = tx0 - 1;
  const int tid = threadIdx.x;

  const float* adjx = adj + (size_t)b * 2 * SZ;
  const float* adjy = adjx + SZ;
  const float* res0 = res + (size_t)b * 2 * SZ;
  const float* res1 = res0 + SZ;

  stage_pair(res0, res1, s_src, xo, yo, tid);
  stage_field(adjx, adjy, s_tile, fy0, fx0, tid);

  const int ly = tid >> 4, lx = tid & 15;
  const int oy = ty0 + ly, ox = tx0 + lx;
  const float RW[4] = {0.25f, 0.75f, 0.75f, 0.25f};
  float wy[4], wx[4];
  float sumy = 0.f, sumx = 0.f;
  #pragma unroll
  for (int d = 0; d < 4; ++d) {
    int g = 2 * oy - 1 + d;
    wy[d] = ((unsigned)g < (unsigned)HW2) ? RW[d] : 0.0f; sumy += wy[d];
    g = 2 * ox - 1 + d;
    wx[d] = ((unsigned)g < (unsigned)HW2) ? RW[d] : 0.0f; sumx += wx[d];
  }
  const float inv = 1.0f / (sumy * sumx);

  __syncthreads();                                 // field + src ready

  PtTaps pt[K_PTS];
  compute_taps(s_tile, fy0, fx0, gx0, gy0, xo, yo, tid, pt);

  __syncthreads();                                 // field reads done; s_tile free

  eval_round(s_src, s_tile, res0, res1, pt, tid);
  __syncthreads();

  float acc0 = 0.0f, acc1 = 0.0f;
  #pragma unroll
  for (int dy = 0; dy < 4; ++dy) {
    float r0 = 0.0f, r1 = 0.0f;
    const int base = (2 * ly + dy) * 34 + 2 * lx;
    #pragma unroll
    for (int dx = 0; dx < 4; ++dx) {
      float2 v = s_tile[base + dx];
      r0 += wx[dx] * v.x;
      r1 += wx[dx] * v.y;
    }
    acc0 += wy[dy] * r0;
    acc1 += wy[dy] * r1;
  }
  size_t o = ((size_t)b * 2) * SZ + (size_t)oy * HW + ox;
  nres[o]      = acc0 * inv + adjx[(size_t)oy * HW + ox];
  nres[o + SZ] = acc1 * inv + adjy[(size_t)oy * HW + ox];
}

extern "C" void kernel_launch(void* const* d_in, const int* in_sizes, int n_in,
                              void* d_out, int out_size, void* d_ws, size_t ws_size,
                              hipStream_t stream) {
  const float* x   = (const float*)d_in[0];  // [2,32,512,512] f32
  const float* res = (const float*)d_in[1];  // [2,2,512,512]  f32
  const float* Wc  = (const float*)d_in[2];  // [2,50,3,3]     f32
  const float* bc  = (const float*)d_in[3];  // [2]            f32
  float* out = (float*)d_out;                // [2,32,512,512] f32

  float* adj  = (float*)d_ws;                // [2,2,512,512]
  float* nres = adj + (size_t)2 * 2 * SZ;    // [2,2,512,512]

  dim3 tile_grid(32, 32, 2);

  // K1: warped_tgt -> out channels 16..31 (fp32 staging for conv)
  warp_img_kernel<<<tile_grid, dim3(256), 0, stream>>>(x, res, out);

  // K2: conv3x3 over [x(0..31) | out(16..31) | res] -> adj, plus fused src passthrough
  conv_kernel<<<tile_grid, dim3(256), 0, stream>>>(x, res, Wc, bc, out, adj);

  // K3: new_res
  new_res_kernel<<<tile_grid, dim3(256), 0, stream>>>(res, adj, nres);

  // K4: hindsight warp -> out channels 16..31 (overwrites staging)
  warp_img_kernel<<<tile_grid, dim3(256), 0, stream>>>(x, nres, out);
}

// Round 8
// 372.635 us; speedup vs baseline: 1.1312x; 1.1312x over previous
//
#include <hip/hip_runtime.h>
#include <hip/hip_bf16.h>
#include <cstdint>
#include <cstddef>

// Problem constants
#define HW   512
#define HW2  1024
#define SZ   (512 * 512)
#define NPT  (34 * 34)   // 1156 warped 1024-res points per 16x16 output tile
#define K_PTS 5          // ceil(1156 / 256)
#define SRCW 36          // staged source window: 36x36
#define NSRC (SRCW * SRCW)   // 1296
#define MARG 9           // window origin = tile_origin - MARG
#define FDIM 18          // staged field window: rows/cols [t0-1, t0+16]
#define NFLD (FDIM * FDIM)   // 324

// jax.image.resize bilinear upsample 512->1024 taps for output index i (0..1023)
struct UpTap { int i0, i1; float w0, w1; };

__device__ __forceinline__ UpTap up_tap(int i) {
  UpTap t;
  int k = i >> 1;
  if ((i & 1) == 0) {
    t.i0 = k - 1; t.i1 = k; t.w0 = 0.25f; t.w1 = 0.75f;
    if (k == 0) { t.i0 = 0; t.w0 = 0.0f; t.w1 = 1.0f; }
  } else {
    t.i0 = k; t.i1 = k + 1; t.w0 = 0.75f; t.w1 = 0.25f;
    if (k == HW - 1) { t.i1 = HW - 1; t.w0 = 1.0f; t.w1 = 0.0f; }
  }
  return t;
}

// Both warp-field components, bilinear-upsampled, served from the staged LDS tile.
__device__ __forceinline__ float2 up_at2(const float2* __restrict__ f,
                                         int yi, int xi, int oy, int ox) {
  UpTap ty = up_tap(yi), tx = up_tap(xi);
  const float2* r0 = f + (ty.i0 - oy) * FDIM - ox;
  const float2* r1 = f + (ty.i1 - oy) * FDIM - ox;
  float2 v00 = r0[tx.i0], v01 = r0[tx.i1];
  float2 v10 = r1[tx.i0], v11 = r1[tx.i1];
  float2 r;
  r.x = ty.w0 * (tx.w0 * v00.x + tx.w1 * v01.x) + ty.w1 * (tx.w0 * v10.x + tx.w1 * v11.x);
  r.y = ty.w0 * (tx.w0 * v00.y + tx.w1 * v01.y) + ty.w1 * (tx.w0 * v10.y + tx.w1 * v11.y);
  return r;
}

// Separable decomposition of (warp-bilinear in 1024-space) o (2x upsample):
// a 3-tap stencil on the 512 grid. Base clamped to [0,509]; out-of-range
// corners get weight 0 (zero padding, mask pre-clamp).
__device__ __forceinline__ void axis_taps(float s, int& base, float& w0, float& w1, float& w2) {
  float f0 = floorf(s);
  int i0 = (int)f0;
  float fr = s - f0;
  int b = (i0 & 1) ? (i0 >> 1) : (i0 >> 1) - 1;
  b = b < 0 ? 0 : (b > (HW - 3) ? (HW - 3) : b);
  float w[3] = {0.0f, 0.0f, 0.0f};
  if ((unsigned)i0 < (unsigned)HW2) {
    UpTap t = up_tap(i0);
    w[t.i0 - b] += (1.0f - fr) * t.w0;
    w[t.i1 - b] += (1.0f - fr) * t.w1;
  }
  if ((unsigned)(i0 + 1) < (unsigned)HW2) {
    UpTap t = up_tap(i0 + 1);
    w[t.i0 - b] += fr * t.w0;
    w[t.i1 - b] += fr * t.w1;
  }
  base = b; w0 = w[0]; w1 = w[1]; w2 = w[2];
}

// Per-point separable 3x3 stencil. locoff >= 0: index into staged 36x36 LDS window.
// locoff < 0: rare fallback, ~locoff = global by*HW+bx offset (displacement > ~8px).
struct PtTaps {
  int   locoff;
  float wy0, wy1, wy2, wx0, wx1, wx2;
};

// Stage the 18x18 field window (fx,fy interleaved) into LDS.
__device__ __forceinline__ void stage_field(const float* __restrict__ fx,
                                            const float* __restrict__ fy,
                                            float2* __restrict__ sf,
                                            int fy0, int fx0, int tid) {
  #pragma unroll
  for (int i = 0; i < 2; ++i) {
    int p = tid + i * 256;
    if (p < NFLD) {
      int r = p / FDIM, c = p % FDIM;
      int gy = fy0 + r; gy = gy < 0 ? 0 : (gy > HW - 1 ? HW - 1 : gy);
      int gx = fx0 + c; gx = gx < 0 ? 0 : (gx > HW - 1 ? HW - 1 : gx);
      size_t o = (size_t)gy * HW + gx;
      sf[p] = make_float2(fx[o], fy[o]);
    }
  }
}

// Taps from the LDS-staged field (no global loads).
__device__ __forceinline__ void compute_taps(const float2* __restrict__ sf,
                                             int fy0, int fx0,
                                             int gx0, int gy0, int xo, int yo, int tid,
                                             PtTaps (&pt)[K_PTS]) {
  #pragma unroll
  for (int i = 0; i < K_PTS; ++i) {
    int p = tid + i * 256;
    pt[i].locoff = 0;
    pt[i].wy0 = pt[i].wy1 = pt[i].wy2 = 0.0f;
    pt[i].wx0 = pt[i].wx1 = pt[i].wx2 = 0.0f;
    if (p < NPT) {
      int ry = p / 34, rx = p % 34;
      int yy = gy0 + ry, xx = gx0 + rx;
      if ((unsigned)yy < (unsigned)HW2 && (unsigned)xx < (unsigned)HW2) {
        float2 d = up_at2(sf, yy, xx, fy0, fx0);
        float sx = (float)xx + 2.0f * d.x;
        float sy = (float)yy + 2.0f * d.y;
        int bx, by;
        axis_taps(sx, bx, pt[i].wx0, pt[i].wx1, pt[i].wx2);
        axis_taps(sy, by, pt[i].wy0, pt[i].wy1, pt[i].wy2);
        int rx_ = bx - xo, ry_ = by - yo;
        if ((unsigned)rx_ <= (unsigned)(SRCW - 3) && (unsigned)ry_ <= (unsigned)(SRCW - 3))
          pt[i].locoff = ry_ * SRCW + rx_;          // in staged window
        else
          pt[i].locoff = ~(by * HW + bx);           // fallback: global offset
      }
    }
  }
}

// Stage a channel pair's 36x36 source window into LDS (float2 interleaved).
__device__ __forceinline__ void stage_pair(const float* __restrict__ p0,
                                           const float* __restrict__ p1,
                                           float2* __restrict__ s_src,
                                           int xo, int yo, int tid) {
  #pragma unroll
  for (int i = 0; i < 6; ++i) {                   // 6*256 = 1536 >= 1296
    int p = tid + i * 256;
    if (p < NSRC) {
      int r = p / SRCW, c = p % SRCW;
      int gy = yo + r; gy = gy < 0 ? 0 : (gy > HW - 1 ? HW - 1 : gy);
      int gx = xo + c; gx = gx < 0 ? 0 : (gx > HW - 1 ? HW - 1 : gx);
      size_t o = (size_t)gy * HW + gx;
      s_src[p] = make_float2(p0[o], p1[o]);
    }
  }
}

__device__ __forceinline__ float eval3_global(const float* __restrict__ pl, int off, const PtTaps& t) {
  const float* p0 = pl + off;
  float r0 = t.wx0 * p0[0]        + t.wx1 * p0[1]          + t.wx2 * p0[2];
  float r1 = t.wx0 * p0[HW]       + t.wx1 * p0[HW + 1]     + t.wx2 * p0[HW + 2];
  float r2 = t.wx0 * p0[2 * HW]   + t.wx1 * p0[2 * HW + 1] + t.wx2 * p0[2 * HW + 2];
  return t.wy0 * r0 + t.wy1 * r1 + t.wy2 * r2;
}

// Evaluate all points of a channel pair from the staged LDS window into s_tile.
__device__ __forceinline__ void eval_round(const float2* __restrict__ s_src,
                                           float2* __restrict__ s_tile,
                                           const float* __restrict__ plane0,
                                           const float* __restrict__ plane1,
                                           const PtTaps (&pt)[K_PTS], int tid) {
  #pragma unroll
  for (int i = 0; i < K_PTS; ++i) {
    int p = tid + i * 256;
    if (p < NPT) {
      const PtTaps t = pt[i];
      float a0, a1;
      if (t.locoff >= 0) {
        const float2* s = s_src + t.locoff;
        float2 v00 = s[0],        v01 = s[1],            v02 = s[2];
        float2 v10 = s[SRCW],     v11 = s[SRCW + 1],     v12 = s[SRCW + 2];
        float2 v20 = s[2 * SRCW], v21 = s[2 * SRCW + 1], v22 = s[2 * SRCW + 2];
        float r00 = t.wx0 * v00.x + t.wx1 * v01.x + t.wx2 * v02.x;
        float r10 = t.wx0 * v10.x + t.wx1 * v11.x + t.wx2 * v12.x;
        float r20 = t.wx0 * v20.x + t.wx1 * v21.x + t.wx2 * v22.x;
        float r01 = t.wx0 * v00.y + t.wx1 * v01.y + t.wx2 * v02.y;
        float r11 = t.wx0 * v10.y + t.wx1 * v11.y + t.wx2 * v12.y;
        float r21 = t.wx0 * v20.y + t.wx1 * v21.y + t.wx2 * v22.y;
        a0 = t.wy0 * r00 + t.wy1 * r10 + t.wy2 * r20;
        a1 = t.wy0 * r01 + t.wy1 * r11 + t.wy2 * r21;
      } else {                                     // ~never taken (|disp| > ~8px)
        int off = ~t.locoff;
        a0 = eval3_global(plane0, off, t);
        a1 = eval3_global(plane1, off, t);
      }
      s_tile[p] = make_float2(a0, a1);
    }
  }
}

// -------------------- K1/K4: res_warp_img(tgt, res_field, rollback=1) --------------------
// Round-1 structure (VGPR=64 invariant) + LDS-staged warp field for the tap phase.
__global__ void warp_img_kernel(const float* __restrict__ x,    // [B,32,512,512]
                                const float* __restrict__ res,  // [B,2,512,512]
                                float* __restrict__ out)        // [B,32,512,512]
{
  __shared__ float2 s_src[NSRC];   // 10368 B
  __shared__ float2 s_tile[NPT];   //  9248 B  (prologue: holds the 18x18 field tile)

  const int b = blockIdx.z;
  const int tx0 = blockIdx.x * 16, ty0 = blockIdx.y * 16;
  const int gx0 = tx0 * 2 - 1, gy0 = ty0 * 2 - 1;
  const int xo = tx0 - MARG, yo = ty0 - MARG;
  const int fy0 = ty0 - 1, fx0 = tx0 - 1;
  const int tid = threadIdx.x;

  const float* resx = res + (size_t)b * 2 * SZ;
  const float* resy = resx + SZ;
  const float* tgt  = x + ((size_t)b * 32 + 16) * SZ;

  // Issue round-0 channel staging + field staging together.
  stage_pair(tgt, tgt + SZ, s_src, xo, yo, tid);
  stage_field(resx, resy, s_tile, fy0, fx0, tid);

  // Downsample stencil weights for this thread's output pixel
  const int ly = tid >> 4, lx = tid & 15;
  const int oy = ty0 + ly, ox = tx0 + lx;
  const float RW[4] = {0.25f, 0.75f, 0.75f, 0.25f};
  float wy[4], wx[4];
  float sumy = 0.f, sumx = 0.f;
  #pragma unroll
  for (int d = 0; d < 4; ++d) {
    int g = 2 * oy - 1 + d;
    wy[d] = ((unsigned)g < (unsigned)HW2) ? RW[d] : 0.0f; sumy += wy[d];
    g = 2 * ox - 1 + d;
    wx[d] = ((unsigned)g < (unsigned)HW2) ? RW[d] : 0.0f; sumx += wx[d];
  }
  const float inv = 1.0f / (sumy * sumx);

  __syncthreads();                                 // field + round-0 src ready

  PtTaps pt[K_PTS];
  compute_taps(s_tile, fy0, fx0, gx0, gy0, xo, yo, tid, pt);

  __syncthreads();                                 // field reads done; s_tile free

  for (int c = 0; c < 16; c += 2) {
    const float* plane0 = tgt + (size_t)c * SZ;
    eval_round(s_src, s_tile, plane0, plane0 + SZ, pt, tid);
    __syncthreads();                               // s_tile ready; s_src free

    if (c < 14)                                    // overlap next staging with phase 3
      stage_pair(plane0 + 2 * SZ, plane0 + 3 * SZ, s_src, xo, yo, tid);

    float acc0 = 0.0f, acc1 = 0.0f;
    #pragma unroll
    for (int dy = 0; dy < 4; ++dy) {
      float r0 = 0.0f, r1 = 0.0f;
      const int base = (2 * ly + dy) * 34 + 2 * lx;
      #pragma unroll
      for (int dx = 0; dx < 4; ++dx) {
        float2 v = s_tile[base + dx];
        r0 += wx[dx] * v.x;
        r1 += wx[dx] * v.y;
      }
      acc0 += wy[dy] * r0;
      acc1 += wy[dy] * r1;
    }
    size_t o = (((size_t)b * 32 + 16 + c) * HW + oy) * HW + ox;
    out[o] = acc0 * inv;
    out[o + SZ] = acc1 * inv;
    __syncthreads();                               // s_src(next) ready; s_tile free
  }
}

// -------------------- K2: 3x3 conv over 50-ch bundle -> 2-ch adj --------------------
// Round-6 proven structure (quad-processed, b32 per-plane halo buffers, T14
// write-late prefetch, VGPR-cheap) with ONE change: weights come straight from
// global Wc with wave-uniform indices -> scalar s_load path, deleting the 900
// per-thread LDS broadcast reads that made round-6's conv LDS-issue-bound.
// Fused src passthrough (out ch 0..15 = halo center taps) kept.
#define CHN 18                     // halo width (16 + 2)
#define CHE (CHN * CHN)            // 324 elements

__global__ void __launch_bounds__(256)
conv_kernel(const float* __restrict__ x,
            const float* __restrict__ res,
            const float* __restrict__ Wc,      // [2,50,3,3]
            const float* __restrict__ bc,      // [2]
            float* __restrict__ out,           // [B,32,512,512]: reads ch16..31 (warped), writes ch0..15
            float* __restrict__ adj)           // [B,2,512,512]
{
  __shared__ float sh[8][CHE];     // two quad-buffers (4 planes each), b32

  const int tid = threadIdx.x;
  const int b = blockIdx.z;
  const int tx0 = blockIdx.x * 16, ty0 = blockIdx.y * 16;
  const int ty = tid >> 4, tx = tid & 15;

  const float* px = x + (size_t)b * 32 * SZ;
  const float* pw = out + ((size_t)b * 32 + 16) * SZ;
  const float* pr = res + (size_t)b * 2 * SZ;

  // Halo-slot addressing (identical for every plane; computed once)
  const int ry0 = tid / CHN, rx0 = tid - ry0 * CHN;
  const int hy0 = ty0 - 1 + ry0, hx0 = tx0 - 1 + rx0;
  const bool ok0 = (unsigned)hy0 < (unsigned)HW && (unsigned)hx0 < (unsigned)HW;
  const int off0 = hy0 * HW + hx0;               // only deref'd under ok0
  const int p1 = tid + 256;
  const bool sl1 = p1 < CHE;                     // tid < 68
  const int ry1 = p1 / CHN, rx1 = p1 - ry1 * CHN;
  const int hy1 = ty0 - 1 + ry1, hx1 = tx0 - 1 + rx1;
  const bool ok1 = sl1 && (unsigned)hy1 < (unsigned)HW && (unsigned)hx1 < (unsigned)HW;
  const int off1 = hy1 * HW + hx1;

  #define PLANE(ic) ((ic) < 32 ? px + (size_t)(ic) * SZ \
                   : (ic) < 48 ? pw + (size_t)((ic) - 32) * SZ \
                   : pr + (size_t)((ic) - 48) * SZ)

  float acc0 = bc[0];
  float acc1 = bc[1];

  float q0[4], q1[4];
  {  // prologue: stage quad 0 (planes 0..3) into sh[0..3]
    #pragma unroll
    for (int j = 0; j < 4; ++j) {
      const float* pl = PLANE(j);
      q0[j] = ok0 ? pl[off0] : 0.f;
      q1[j] = ok1 ? pl[off1] : 0.f;
    }
    #pragma unroll
    for (int j = 0; j < 4; ++j) {
      sh[j][tid] = q0[j];
      if (sl1) sh[j][p1] = q1[j];
    }
  }

  const size_t pix = (size_t)(ty0 + ty) * HW + (tx0 + tx);

  for (int kk = 0; kk < 12; ++kk) {
    __syncthreads();                      // current quad ready; other quad free
    if (kk < 11) {                        // issue next quad's loads before compute (T14)
      #pragma unroll
      for (int j = 0; j < 4; ++j) {
        const float* pl = PLANE(4 * kk + 4 + j);
        q0[j] = ok0 ? pl[off0] : 0.f;
        q1[j] = ok1 ? pl[off1] : 0.f;
      }
    } else {                              // last: stage the res pair (ch 48,49)
      #pragma unroll
      for (int j = 0; j < 2; ++j) {
        const float* pl = PLANE(48 + j);
        q0[j] = ok0 ? pl[off0] : 0.f;
        q1[j] = ok1 ? pl[off1] : 0.f;
      }
    }

    const int cur = (kk & 1) * 4;
    const float* w0 = Wc + (size_t)(4 * kk) * 9;        // uniform index -> s_load
    const float* w1 = Wc + 450 + (size_t)(4 * kk) * 9;
    float cen[4];
    #pragma unroll
    for (int ky = 0; ky < 3; ++ky) {
      #pragma unroll
      for (int kx = 0; kx < 3; ++kx) {
        const int hoff = (ty + ky) * CHN + tx + kx;
        const int widx = ky * 3 + kx;
        #pragma unroll
        for (int j = 0; j < 4; ++j) {
          float v = sh[cur + j][hoff];
          if (ky == 1 && kx == 1) cen[j] = v;
          acc0 += v * w0[j * 9 + widx];
          acc1 += v * w1[j * 9 + widx];
        }
      }
    }

    if (kk < 4) {                         // fused K0: out ch 4kk..4kk+3 = x ch 4kk..4kk+3
      #pragma unroll
      for (int j = 0; j < 4; ++j)
        out[((size_t)b * 32 + 4 * kk + j) * SZ + pix] = cen[j];
    }

    const int nxt = cur ^ 4;              // write-late into the other quad-buffer
    if (kk < 11) {
      #pragma unroll
      for (int j = 0; j < 4; ++j) {
        sh[nxt + j][tid] = q0[j];
        if (sl1) sh[nxt + j][p1] = q1[j];
      }
    } else {
      #pragma unroll
      for (int j = 0; j < 2; ++j) {
        sh[nxt + j][tid] = q0[j];
        if (sl1) sh[nxt + j][p1] = q1[j];
      }
    }
  }

  // epilogue: res pair (ch 48,49) sits in sh[0],sh[1]
  __syncthreads();
  {
    const float* w0 = Wc + (size_t)48 * 9;
    const float* w1 = Wc + 450 + (size_t)48 * 9;
    #pragma unroll
    for (int ky = 0; ky < 3; ++ky) {
      #pragma unroll
      for (int kx = 0; kx < 3; ++kx) {
        const int hoff = (ty + ky) * CHN + tx + kx;
        const int widx = ky * 3 + kx;
        #pragma unroll
        for (int j = 0; j < 2; ++j) {
          float v = sh[j][hoff];
          acc0 += v * w0[j * 9 + widx];
          acc1 += v * w1[j * 9 + widx];
        }
      }
    }
  }
  #undef PLANE

  adj[((size_t)b * 2 + 0) * SZ + pix] = acc0;
  adj[((size_t)b * 2 + 1) * SZ + pix] = acc1;
}

// -------------------- K3: new_res = adj + downsample(warp(up(res), 2*up(adj))) --------------------
// (the reference's *2 on the warped field values and the *0.5 after downsample cancel exactly)
__global__ void new_res_kernel(const float* __restrict__ res,  // [B,2,512,512]
                               const float* __restrict__ adj,  // [B,2,512,512]
                               float* __restrict__ nres)       // [B,2,512,512]
{
  __shared__ float2 s_src[NSRC];
  __shared__ float2 s_tile[NPT];

  const int b = blockIdx.z;
  const int tx0 = blockIdx.x * 16, ty0 = blockIdx.y * 16;
  const int gx0 = tx0 * 2 - 1, gy0 = ty0 * 2 - 1;
  const int xo = tx0 - MARG, yo = ty0 - MARG;
  const int fy0 = ty0 - 1, fx0 = tx0 - 1;
  const int tid = threadIdx.x;

  const float* adjx = adj + (size_t)b * 2 * SZ;
  const float* adjy = adjx + SZ;
  const float* res0 = res + (size_t)b * 2 * SZ;
  const float* res1 = res0 + SZ;

  stage_pair(res0, res1, s_src, xo, yo, tid);
  stage_field(adjx, adjy, s_tile, fy0, fx0, tid);

  const int ly = tid >> 4, lx = tid & 15;
  const int oy = ty0 + ly, ox = tx0 + lx;
  const float RW[4] = {0.25f, 0.75f, 0.75f, 0.25f};
  float wy[4], wx[4];
  float sumy = 0.f, sumx = 0.f;
  #pragma unroll
  for (int d = 0; d < 4; ++d) {
    int g = 2 * oy - 1 + d;
    wy[d] = ((unsigned)g < (unsigned)HW2) ? RW[d] : 0.0f; sumy += wy[d];
    g = 2 * ox - 1 + d;
    wx[d] = ((unsigned)g < (unsigned)HW2) ? RW[d] : 0.0f; sumx += wx[d];
  }
  const float inv = 1.0f / (sumy * sumx);

  __syncthreads();                                 // field + src ready

  PtTaps pt[K_PTS];
  compute_taps(s_tile, fy0, fx0, gx0, gy0, xo, yo, tid, pt);

  __syncthreads();                                 // field reads done; s_tile free

  eval_round(s_src, s_tile, res0, res1, pt, tid);
  __syncthreads();

  float acc0 = 0.0f, acc1 = 0.0f;
  #pragma unroll
  for (int dy = 0; dy < 4; ++dy) {
    float r0 = 0.0f, r1 = 0.0f;
    const int base = (2 * ly + dy) * 34 + 2 * lx;
    #pragma unroll
    for (int dx = 0; dx < 4; ++dx) {
      float2 v = s_tile[base + dx];
      r0 += wx[dx] * v.x;
      r1 += wx[dx] * v.y;
    }
    acc0 += wy[dy] * r0;
    acc1 += wy[dy] * r1;
  }
  size_t o = ((size_t)b * 2) * SZ + (size_t)oy * HW + ox;
  nres[o]      = acc0 * inv + adjx[(size_t)oy * HW + ox];
  nres[o + SZ] = acc1 * inv + adjy[(size_t)oy * HW + ox];
}

extern "C" void kernel_launch(void* const* d_in, const int* in_sizes, int n_in,
                              void* d_out, int out_size, void* d_ws, size_t ws_size,
                              hipStream_t stream) {
  const float* x   = (const float*)d_in[0];  // [2,32,512,512] f32
  const float* res = (const float*)d_in[1];  // [2,2,512,512]  f32
  const float* Wc  = (const float*)d_in[2];  // [2,50,3,3]     f32
  const float* bc  = (const float*)d_in[3];  // [2]            f32
  float* out = (float*)d_out;                // [2,32,512,512] f32

  float* adj  = (float*)d_ws;                // [2,2,512,512]
  float* nres = adj + (size_t)2 * 2 * SZ;    // [2,2,512,512]

  dim3 tile_grid(32, 32, 2);

  // K1: warped_tgt -> out channels 16..31 (fp32 staging for conv)
  warp_img_kernel<<<tile_grid, dim3(256), 0, stream>>>(x, res, out);

  // K2: conv3x3 over [x(0..31) | out(16..31) | res] -> adj, plus fused src passthrough
  conv_kernel<<<tile_grid, dim3(256), 0, stream>>>(x, res, Wc, bc, out, adj);

  // K3: new_res
  new_res_kernel<<<tile_grid, dim3(256), 0, stream>>>(res, adj, nres);

  // K4: hindsight warp -> out channels 16..31 (overwrites staging)
  warp_img_kernel<<<tile_grid, dim3(256), 0, stream>>>(x, nres, out);
}

// Round 9
// 370.114 us; speedup vs baseline: 1.1389x; 1.0068x over previous
//
#include <hip/hip_runtime.h>
#include <hip/hip_bf16.h>
#include <cstdint>
#include <cstddef>

// Problem constants
#define HW   512
#define HW2  1024
#define SZ   (512 * 512)
#define NPT  (34 * 34)   // 1156 warped 1024-res points per 16x16 output tile
#define K_PTS 5          // ceil(1156 / 256)
#define SRCW 36          // staged source window: 36x36
#define NSRC (SRCW * SRCW)   // 1296
#define MARG 9           // window origin = tile_origin - MARG
#define FDIM 18          // staged field window: rows/cols [t0-1, t0+16]
#define NFLD (FDIM * FDIM)   // 324
// Fused-K4 prologue windows
#define SRCW2 38                 // res window for the nres point grid
#define NSRC2 (SRCW2 * SRCW2)    // 1444
#define MARG2 10                 // res window origin = tile_origin - MARG2
#define ADIM 20                  // adj window [t0-2, t0+17]
#define NADJ (ADIM * ADIM)       // 400

// jax.image.resize bilinear upsample 512->1024 taps for output index i (0..1023)
struct UpTap { int i0, i1; float w0, w1; };

__device__ __forceinline__ UpTap up_tap(int i) {
  UpTap t;
  int k = i >> 1;
  if ((i & 1) == 0) {
    t.i0 = k - 1; t.i1 = k; t.w0 = 0.25f; t.w1 = 0.75f;
    if (k == 0) { t.i0 = 0; t.w0 = 0.0f; t.w1 = 1.0f; }
  } else {
    t.i0 = k; t.i1 = k + 1; t.w0 = 0.75f; t.w1 = 0.25f;
    if (k == HW - 1) { t.i1 = HW - 1; t.w0 = 1.0f; t.w1 = 0.0f; }
  }
  return t;
}

// Both field components, bilinear-upsampled, from a staged LDS tile (runtime stride).
__device__ __forceinline__ float2 up_at2s(const float2* __restrict__ f,
                                          int yi, int xi, int oy, int ox, int stride) {
  UpTap ty = up_tap(yi), tx = up_tap(xi);
  const float2* r0 = f + (ty.i0 - oy) * stride - ox;
  const float2* r1 = f + (ty.i1 - oy) * stride - ox;
  float2 v00 = r0[tx.i0], v01 = r0[tx.i1];
  float2 v10 = r1[tx.i0], v11 = r1[tx.i1];
  float2 r;
  r.x = ty.w0 * (tx.w0 * v00.x + tx.w1 * v01.x) + ty.w1 * (tx.w0 * v10.x + tx.w1 * v11.x);
  r.y = ty.w0 * (tx.w0 * v00.y + tx.w1 * v01.y) + ty.w1 * (tx.w0 * v10.y + tx.w1 * v11.y);
  return r;
}

// Separable decomposition of (warp-bilinear in 1024-space) o (2x upsample):
// a 3-tap stencil on the 512 grid. Base clamped to [0,509]; out-of-range
// corners get weight 0 (zero padding, mask pre-clamp).
__device__ __forceinline__ void axis_taps(float s, int& base, float& w0, float& w1, float& w2) {
  float f0 = floorf(s);
  int i0 = (int)f0;
  float fr = s - f0;
  int b = (i0 & 1) ? (i0 >> 1) : (i0 >> 1) - 1;
  b = b < 0 ? 0 : (b > (HW - 3) ? (HW - 3) : b);
  float w[3] = {0.0f, 0.0f, 0.0f};
  if ((unsigned)i0 < (unsigned)HW2) {
    UpTap t = up_tap(i0);
    w[t.i0 - b] += (1.0f - fr) * t.w0;
    w[t.i1 - b] += (1.0f - fr) * t.w1;
  }
  if ((unsigned)(i0 + 1) < (unsigned)HW2) {
    UpTap t = up_tap(i0 + 1);
    w[t.i0 - b] += fr * t.w0;
    w[t.i1 - b] += fr * t.w1;
  }
  base = b; w0 = w[0]; w1 = w[1]; w2 = w[2];
}

// Per-point separable 3x3 stencil. locoff >= 0: index into staged 36x36 LDS window.
// locoff < 0: rare fallback, ~locoff = global by*HW+bx offset (displacement > ~8px).
struct PtTaps {
  int   locoff;
  float wy0, wy1, wy2, wx0, wx1, wx2;
};

// Stage the 18x18 field window (fx,fy interleaved) into LDS.
__device__ __forceinline__ void stage_field(const float* __restrict__ fx,
                                            const float* __restrict__ fy,
                                            float2* __restrict__ sf,
                                            int fy0, int fx0, int tid) {
  #pragma unroll
  for (int i = 0; i < 2; ++i) {
    int p = tid + i * 256;
    if (p < NFLD) {
      int r = p / FDIM, c = p % FDIM;
      int gy = fy0 + r; gy = gy < 0 ? 0 : (gy > HW - 1 ? HW - 1 : gy);
      int gx = fx0 + c; gx = gx < 0 ? 0 : (gx > HW - 1 ? HW - 1 : gx);
      size_t o = (size_t)gy * HW + gx;
      sf[p] = make_float2(fx[o], fy[o]);
    }
  }
}

// Taps from an LDS-staged 18x18 field (no global loads).
__device__ __forceinline__ void compute_taps(const float2* __restrict__ sf,
                                             int fy0, int fx0,
                                             int gx0, int gy0, int xo, int yo, int tid,
                                             PtTaps (&pt)[K_PTS]) {
  #pragma unroll
  for (int i = 0; i < K_PTS; ++i) {
    int p = tid + i * 256;
    pt[i].locoff = 0;
    pt[i].wy0 = pt[i].wy1 = pt[i].wy2 = 0.0f;
    pt[i].wx0 = pt[i].wx1 = pt[i].wx2 = 0.0f;
    if (p < NPT) {
      int ry = p / 34, rx = p % 34;
      int yy = gy0 + ry, xx = gx0 + rx;
      if ((unsigned)yy < (unsigned)HW2 && (unsigned)xx < (unsigned)HW2) {
        float2 d = up_at2s(sf, yy, xx, fy0, fx0, FDIM);
        float sx = (float)xx + 2.0f * d.x;
        float sy = (float)yy + 2.0f * d.y;
        int bx, by;
        axis_taps(sx, bx, pt[i].wx0, pt[i].wx1, pt[i].wx2);
        axis_taps(sy, by, pt[i].wy0, pt[i].wy1, pt[i].wy2);
        int rx_ = bx - xo, ry_ = by - yo;
        if ((unsigned)rx_ <= (unsigned)(SRCW - 3) && (unsigned)ry_ <= (unsigned)(SRCW - 3))
          pt[i].locoff = ry_ * SRCW + rx_;          // in staged window
        else
          pt[i].locoff = ~(by * HW + bx);           // fallback: global offset
      }
    }
  }
}

// Stage a channel pair's 36x36 source window into LDS (float2 interleaved).
__device__ __forceinline__ void stage_pair(const float* __restrict__ p0,
                                           const float* __restrict__ p1,
                                           float2* __restrict__ s_src,
                                           int xo, int yo, int tid) {
  #pragma unroll
  for (int i = 0; i < 6; ++i) {                   // 6*256 = 1536 >= 1296
    int p = tid + i * 256;
    if (p < NSRC) {
      int r = p / SRCW, c = p % SRCW;
      int gy = yo + r; gy = gy < 0 ? 0 : (gy > HW - 1 ? HW - 1 : gy);
      int gx = xo + c; gx = gx < 0 ? 0 : (gx > HW - 1 ? HW - 1 : gx);
      size_t o = (size_t)gy * HW + gx;
      s_src[p] = make_float2(p0[o], p1[o]);
    }
  }
}

__device__ __forceinline__ float eval3_global(const float* __restrict__ pl, int off, const PtTaps& t) {
  const float* p0 = pl + off;
  float r0 = t.wx0 * p0[0]        + t.wx1 * p0[1]          + t.wx2 * p0[2];
  float r1 = t.wx0 * p0[HW]       + t.wx1 * p0[HW + 1]     + t.wx2 * p0[HW + 2];
  float r2 = t.wx0 * p0[2 * HW]   + t.wx1 * p0[2 * HW + 1] + t.wx2 * p0[2 * HW + 2];
  return t.wy0 * r0 + t.wy1 * r1 + t.wy2 * r2;
}

// Evaluate all points of a channel pair from the staged LDS window into s_tile.
__device__ __forceinline__ void eval_round(const float2* __restrict__ s_src,
                                           float2* __restrict__ s_tile,
                                           const float* __restrict__ plane0,
                                           const float* __restrict__ plane1,
                                           const PtTaps (&pt)[K_PTS], int tid) {
  #pragma unroll
  for (int i = 0; i < K_PTS; ++i) {
    int p = tid + i * 256;
    if (p < NPT) {
      const PtTaps t = pt[i];
      float a0, a1;
      if (t.locoff >= 0) {
        const float2* s = s_src + t.locoff;
        float2 v00 = s[0],        v01 = s[1],            v02 = s[2];
        float2 v10 = s[SRCW],     v11 = s[SRCW + 1],     v12 = s[SRCW + 2];
        float2 v20 = s[2 * SRCW], v21 = s[2 * SRCW + 1], v22 = s[2 * SRCW + 2];
        float r00 = t.wx0 * v00.x + t.wx1 * v01.x + t.wx2 * v02.x;
        float r10 = t.wx0 * v10.x + t.wx1 * v11.x + t.wx2 * v12.x;
        float r20 = t.wx0 * v20.x + t.wx1 * v21.x + t.wx2 * v22.x;
        float r01 = t.wx0 * v00.y + t.wx1 * v01.y + t.wx2 * v02.y;
        float r11 = t.wx0 * v10.y + t.wx1 * v11.y + t.wx2 * v12.y;
        float r21 = t.wx0 * v20.y + t.wx1 * v21.y + t.wx2 * v22.y;
        a0 = t.wy0 * r00 + t.wy1 * r10 + t.wy2 * r20;
        a1 = t.wy0 * r01 + t.wy1 * r11 + t.wy2 * r21;
      } else {                                     // ~never taken (|disp| > ~8px)
        int off = ~t.locoff;
        a0 = eval3_global(plane0, off, t);
        a1 = eval3_global(plane1, off, t);
      }
      s_tile[p] = make_float2(a0, a1);
    }
  }
}

// -------------------- K1: res_warp_img(tgt, res, rollback=1) --------------------
// Round-1 structure (VGPR=64 invariant) + LDS-staged warp field for the tap phase.
__global__ void warp_img_kernel(const float* __restrict__ x,    // [B,32,512,512]
                                const float* __restrict__ res,  // [B,2,512,512]
                                float* __restrict__ out)        // [B,32,512,512]
{
  __shared__ float2 s_src[NSRC];   // 10368 B
  __shared__ float2 s_tile[NPT];   //  9248 B  (prologue: holds the 18x18 field tile)

  const int b = blockIdx.z;
  const int tx0 = blockIdx.x * 16, ty0 = blockIdx.y * 16;
  const int gx0 = tx0 * 2 - 1, gy0 = ty0 * 2 - 1;
  const int xo = tx0 - MARG, yo = ty0 - MARG;
  const int fy0 = ty0 - 1, fx0 = tx0 - 1;
  const int tid = threadIdx.x;

  const float* resx = res + (size_t)b * 2 * SZ;
  const float* resy = resx + SZ;
  const float* tgt  = x + ((size_t)b * 32 + 16) * SZ;

  // Issue round-0 channel staging + field staging together.
  stage_pair(tgt, tgt + SZ, s_src, xo, yo, tid);
  stage_field(resx, resy, s_tile, fy0, fx0, tid);

  // Downsample stencil weights for this thread's output pixel
  const int ly = tid >> 4, lx = tid & 15;
  const int oy = ty0 + ly, ox = tx0 + lx;
  const float RW[4] = {0.25f, 0.75f, 0.75f, 0.25f};
  float wy[4], wx[4];
  float sumy = 0.f, sumx = 0.f;
  #pragma unroll
  for (int d = 0; d < 4; ++d) {
    int g = 2 * oy - 1 + d;
    wy[d] = ((unsigned)g < (unsigned)HW2) ? RW[d] : 0.0f; sumy += wy[d];
    g = 2 * ox - 1 + d;
    wx[d] = ((unsigned)g < (unsigned)HW2) ? RW[d] : 0.0f; sumx += wx[d];
  }
  const float inv = 1.0f / (sumy * sumx);

  __syncthreads();                                 // field + round-0 src ready

  PtTaps pt[K_PTS];
  compute_taps(s_tile, fy0, fx0, gx0, gy0, xo, yo, tid, pt);

  __syncthreads();                                 // field reads done; s_tile free

  for (int c = 0; c < 16; c += 2) {
    const float* plane0 = tgt + (size_t)c * SZ;
    eval_round(s_src, s_tile, plane0, plane0 + SZ, pt, tid);
    __syncthreads();                               // s_tile ready; s_src free

    if (c < 14)                                    // overlap next staging with phase 3
      stage_pair(plane0 + 2 * SZ, plane0 + 3 * SZ, s_src, xo, yo, tid);

    float acc0 = 0.0f, acc1 = 0.0f;
    #pragma unroll
    for (int dy = 0; dy < 4; ++dy) {
      float r0 = 0.0f, r1 = 0.0f;
      const int base = (2 * ly + dy) * 34 + 2 * lx;
      #pragma unroll
      for (int dx = 0; dx < 4; ++dx) {
        float2 v = s_tile[base + dx];
        r0 += wx[dx] * v.x;
        r1 += wx[dx] * v.y;
      }
      acc0 += wy[dy] * r0;
      acc1 += wy[dy] * r1;
    }
    size_t o = (((size_t)b * 32 + 16 + c) * HW + oy) * HW + ox;
    out[o] = acc0 * inv;
    out[o + SZ] = acc1 * inv;
    __syncthreads();                               // s_src(next) ready; s_tile free
  }
}

// -------------------- K2: 3x3 conv over 50-ch bundle -> 2-ch adj --------------------
// Round-8 structure unchanged (quad-processed b32 halos, global-weight s_load path,
// fused src passthrough).
#define CHN 18                     // halo width (16 + 2)
#define CHE (CHN * CHN)            // 324 elements

__global__ void __launch_bounds__(256)
conv_kernel(const float* __restrict__ x,
            const float* __restrict__ res,
            const float* __restrict__ Wc,      // [2,50,3,3]
            const float* __restrict__ bc,      // [2]
            float* __restrict__ out,           // [B,32,512,512]: reads ch16..31 (warped), writes ch0..15
            float* __restrict__ adj)           // [B,2,512,512]
{
  __shared__ float sh[8][CHE];     // two quad-buffers (4 planes each), b32

  const int tid = threadIdx.x;
  const int b = blockIdx.z;
  const int tx0 = blockIdx.x * 16, ty0 = blockIdx.y * 16;
  const int ty = tid >> 4, tx = tid & 15;

  const float* px = x + (size_t)b * 32 * SZ;
  const float* pw = out + ((size_t)b * 32 + 16) * SZ;
  const float* pr = res + (size_t)b * 2 * SZ;

  const int ry0 = tid / CHN, rx0 = tid - ry0 * CHN;
  const int hy0 = ty0 - 1 + ry0, hx0 = tx0 - 1 + rx0;
  const bool ok0 = (unsigned)hy0 < (unsigned)HW && (unsigned)hx0 < (unsigned)HW;
  const int off0 = hy0 * HW + hx0;
  const int p1 = tid + 256;
  const bool sl1 = p1 < CHE;
  const int ry1 = p1 / CHN, rx1 = p1 - ry1 * CHN;
  const int hy1 = ty0 - 1 + ry1, hx1 = tx0 - 1 + rx1;
  const bool ok1 = sl1 && (unsigned)hy1 < (unsigned)HW && (unsigned)hx1 < (unsigned)HW;
  const int off1 = hy1 * HW + hx1;

  #define PLANE(ic) ((ic) < 32 ? px + (size_t)(ic) * SZ \
                   : (ic) < 48 ? pw + (size_t)((ic) - 32) * SZ \
                   : pr + (size_t)((ic) - 48) * SZ)

  float acc0 = bc[0];
  float acc1 = bc[1];

  float q0[4], q1[4];
  {
    #pragma unroll
    for (int j = 0; j < 4; ++j) {
      const float* pl = PLANE(j);
      q0[j] = ok0 ? pl[off0] : 0.f;
      q1[j] = ok1 ? pl[off1] : 0.f;
    }
    #pragma unroll
    for (int j = 0; j < 4; ++j) {
      sh[j][tid] = q0[j];
      if (sl1) sh[j][p1] = q1[j];
    }
  }

  const size_t pix = (size_t)(ty0 + ty) * HW + (tx0 + tx);

  for (int kk = 0; kk < 12; ++kk) {
    __syncthreads();
    if (kk < 11) {
      #pragma unroll
      for (int j = 0; j < 4; ++j) {
        const float* pl = PLANE(4 * kk + 4 + j);
        q0[j] = ok0 ? pl[off0] : 0.f;
        q1[j] = ok1 ? pl[off1] : 0.f;
      }
    } else {
      #pragma unroll
      for (int j = 0; j < 2; ++j) {
        const float* pl = PLANE(48 + j);
        q0[j] = ok0 ? pl[off0] : 0.f;
        q1[j] = ok1 ? pl[off1] : 0.f;
      }
    }

    const int cur = (kk & 1) * 4;
    const float* w0 = Wc + (size_t)(4 * kk) * 9;        // uniform index -> s_load
    const float* w1 = Wc + 450 + (size_t)(4 * kk) * 9;
    float cen[4];
    #pragma unroll
    for (int ky = 0; ky < 3; ++ky) {
      #pragma unroll
      for (int kx = 0; kx < 3; ++kx) {
        const int hoff = (ty + ky) * CHN + tx + kx;
        const int widx = ky * 3 + kx;
        #pragma unroll
        for (int j = 0; j < 4; ++j) {
          float v = sh[cur + j][hoff];
          if (ky == 1 && kx == 1) cen[j] = v;
          acc0 += v * w0[j * 9 + widx];
          acc1 += v * w1[j * 9 + widx];
        }
      }
    }

    if (kk < 4) {
      #pragma unroll
      for (int j = 0; j < 4; ++j)
        out[((size_t)b * 32 + 4 * kk + j) * SZ + pix] = cen[j];
    }

    const int nxt = cur ^ 4;
    if (kk < 11) {
      #pragma unroll
      for (int j = 0; j < 4; ++j) {
        sh[nxt + j][tid] = q0[j];
        if (sl1) sh[nxt + j][p1] = q1[j];
      }
    } else {
      #pragma unroll
      for (int j = 0; j < 2; ++j) {
        sh[nxt + j][tid] = q0[j];
        if (sl1) sh[nxt + j][p1] = q1[j];
      }
    }
  }

  __syncthreads();
  {
    const float* w0 = Wc + (size_t)48 * 9;
    const float* w1 = Wc + 450 + (size_t)48 * 9;
    #pragma unroll
    for (int ky = 0; ky < 3; ++ky) {
      #pragma unroll
      for (int kx = 0; kx < 3; ++kx) {
        const int hoff = (ty + ky) * CHN + tx + kx;
        const int widx = ky * 3 + kx;
        #pragma unroll
        for (int j = 0; j < 2; ++j) {
          float v = sh[j][hoff];
          acc0 += v * w0[j * 9 + widx];
          acc1 += v * w1[j * 9 + widx];
        }
      }
    }
  }
  #undef PLANE

  adj[((size_t)b * 2 + 0) * SZ + pix] = acc0;
  adj[((size_t)b * 2 + 1) * SZ + pix] = acc1;
}

// -------------------- K4 (fused K3+K4): hindsight warp --------------------
// Prologue computes this tile's 18x18 nres field window entirely in LDS
// (replicating new_res_kernel's arithmetic), then runs the standard warp.
// Eliminates the separate new_res kernel launch + its global round-trip.
__global__ void hindsight_kernel(const float* __restrict__ x,    // [B,32,512,512]
                                 const float* __restrict__ res,  // [B,2,512,512]
                                 const float* __restrict__ adj,  // [B,2,512,512]
                                 float* __restrict__ out)        // [B,32,512,512]
{
  __shared__ float2 sA[NSRC2];  // P1: nres point grid (1444) | main: s_src (1296)
  __shared__ float2 sB[NSRC2];  // P0: res 38x38 window      | main: s_tile (1156)
  __shared__ float2 sC[NADJ];   // adj 20x20 window
  __shared__ float2 sF[NFLD];   // 18x18 nres field tile (lives whole kernel)

  const int b = blockIdx.z;
  const int tx0 = blockIdx.x * 16, ty0 = blockIdx.y * 16;
  const int gx0 = tx0 * 2 - 1, gy0 = ty0 * 2 - 1;
  const int xo = tx0 - MARG, yo = ty0 - MARG;
  const int fy0 = ty0 - 1, fx0 = tx0 - 1;
  const int yo2 = ty0 - MARG2, xo2 = tx0 - MARG2;
  const int tid = threadIdx.x;

  const float* adjx = adj + (size_t)b * 2 * SZ;
  const float* adjy = adjx + SZ;
  const float* res0 = res + (size_t)b * 2 * SZ;
  const float* res1 = res0 + SZ;
  const float* tgt  = x + ((size_t)b * 32 + 16) * SZ;

  // ---- P0: stage res 38x38 -> sB, adj 20x20 -> sC
  #pragma unroll
  for (int i = 0; i < 6; ++i) {
    int p = tid + i * 256;
    if (p < NSRC2) {
      int r = p / SRCW2, c = p % SRCW2;
      int gy = yo2 + r; gy = gy < 0 ? 0 : (gy > HW - 1 ? HW - 1 : gy);
      int gx = xo2 + c; gx = gx < 0 ? 0 : (gx > HW - 1 ? HW - 1 : gx);
      size_t o = (size_t)gy * HW + gx;
      sB[p] = make_float2(res0[o], res1[o]);
    }
  }
  #pragma unroll
  for (int i = 0; i < 2; ++i) {
    int p = tid + i * 256;
    if (p < NADJ) {
      int r = p / ADIM, c = p % ADIM;
      int gy = ty0 - 2 + r; gy = gy < 0 ? 0 : (gy > HW - 1 ? HW - 1 : gy);
      int gx = tx0 - 2 + c; gx = gx < 0 ? 0 : (gx > HW - 1 ? HW - 1 : gx);
      size_t o = (size_t)gy * HW + gx;
      sC[p] = make_float2(adjx[o], adjy[o]);
    }
  }

  // Downsample stencil weights for this thread's output pixel (main phase)
  const int ly = tid >> 4, lx = tid & 15;
  const int oy = ty0 + ly, ox = tx0 + lx;
  const float RW[4] = {0.25f, 0.75f, 0.75f, 0.25f};
  float wy[4], wx[4];
  float sumy = 0.f, sumx = 0.f;
  #pragma unroll
  for (int d = 0; d < 4; ++d) {
    int g = 2 * oy - 1 + d;
    wy[d] = ((unsigned)g < (unsigned)HW2) ? RW[d] : 0.0f; sumy += wy[d];
    g = 2 * ox - 1 + d;
    wx[d] = ((unsigned)g < (unsigned)HW2) ? RW[d] : 0.0f; sumx += wx[d];
  }
  const float inv = 1.0f / (sumy * sumx);

  __syncthreads();                                 // sB, sC ready

  // ---- P1: evaluate the 38x38 nres point grid -> sA
  {
    const int qy0 = 2 * fy0 - 1, qx0 = 2 * fx0 - 1;
    #pragma unroll
    for (int i = 0; i < 6; ++i) {
      int p = tid + i * 256;
      if (p < NSRC2) {
        int r = p / SRCW2, c = p % SRCW2;
        int qy = qy0 + r, qx = qx0 + c;
        float a0 = 0.f, a1 = 0.f;
        if ((unsigned)qy < (unsigned)HW2 && (unsigned)qx < (unsigned)HW2) {
          float2 d = up_at2s(sC, qy, qx, ty0 - 2, tx0 - 2, ADIM);
          float sxx = (float)qx + 2.0f * d.x;
          float syy = (float)qy + 2.0f * d.y;
          PtTaps t;
          int bx, by;
          axis_taps(sxx, bx, t.wx0, t.wx1, t.wx2);
          axis_taps(syy, by, t.wy0, t.wy1, t.wy2);
          int rx_ = bx - xo2, ry_ = by - yo2;
          if ((unsigned)rx_ <= (unsigned)(SRCW2 - 3) && (unsigned)ry_ <= (unsigned)(SRCW2 - 3)) {
            const float2* s = sB + ry_ * SRCW2 + rx_;
            float2 v00 = s[0],         v01 = s[1],             v02 = s[2];
            float2 v10 = s[SRCW2],     v11 = s[SRCW2 + 1],     v12 = s[SRCW2 + 2];
            float2 v20 = s[2 * SRCW2], v21 = s[2 * SRCW2 + 1], v22 = s[2 * SRCW2 + 2];
            float r00 = t.wx0 * v00.x + t.wx1 * v01.x + t.wx2 * v02.x;
            float r10 = t.wx0 * v10.x + t.wx1 * v11.x + t.wx2 * v12.x;
            float r20 = t.wx0 * v20.x + t.wx1 * v21.x + t.wx2 * v22.x;
            float r01 = t.wx0 * v00.y + t.wx1 * v01.y + t.wx2 * v02.y;
            float r11 = t.wx0 * v10.y + t.wx1 * v11.y + t.wx2 * v12.y;
            float r21 = t.wx0 * v20.y + t.wx1 * v21.y + t.wx2 * v22.y;
            a0 = t.wy0 * r00 + t.wy1 * r10 + t.wy2 * r20;
            a1 = t.wy0 * r01 + t.wy1 * r11 + t.wy2 * r21;
          } else {                                 // ~never taken
            int off = by * HW + bx;
            a0 = eval3_global(res0, off, t);
            a1 = eval3_global(res1, off, t);
          }
        }
        sA[p] = make_float2(a0, a1);
      }
    }
  }
  __syncthreads();                                 // sA (point grid) ready

  // ---- P2: downsample + adj-center add -> sF (18x18 nres tile)
  #pragma unroll
  for (int i = 0; i < 2; ++i) {
    int p = tid + i * 256;
    if (p < NFLD) {
      int pr = p / FDIM, pc = p % FDIM;
      int py = fy0 + pr; py = py < 0 ? 0 : (py > HW - 1 ? HW - 1 : py);
      int px = fx0 + pc; px = px < 0 ? 0 : (px > HW - 1 ? HW - 1 : px);
      float wyv[4], wxv[4];
      float sy = 0.f, sx = 0.f;
      #pragma unroll
      for (int d = 0; d < 4; ++d) {
        int g = 2 * py - 1 + d;
        wyv[d] = ((unsigned)g < (unsigned)HW2) ? RW[d] : 0.0f; sy += wyv[d];
        g = 2 * px - 1 + d;
        wxv[d] = ((unsigned)g < (unsigned)HW2) ? RW[d] : 0.0f; sx += wxv[d];
      }
      float inv2 = 1.0f / (sy * sx);
      float a0 = 0.f, a1 = 0.f;
      #pragma unroll
      for (int dy = 0; dy < 4; ++dy) {
        float r0 = 0.f, r1 = 0.f;
        const int base = (2 * (py - fy0) + dy) * SRCW2 + 2 * (px - fx0);
        #pragma unroll
        for (int dx = 0; dx < 4; ++dx) {
          float2 v = sA[base + dx];
          r0 += wxv[dx] * v.x;
          r1 += wxv[dx] * v.y;
        }
        a0 += wyv[dy] * r0;
        a1 += wyv[dy] * r1;
      }
      float2 ac = sC[(py - (ty0 - 2)) * ADIM + (px - (tx0 - 2))];
      sF[p] = make_float2(a0 * inv2 + ac.x, a1 * inv2 + ac.y);
    }
  }
  __syncthreads();                                 // sF ready; sA, sB free

  // ---- main warp phase (identical to warp_img_kernel, field = sF)
  stage_pair(tgt, tgt + SZ, sA, xo, yo, tid);      // round-0 channel staging

  PtTaps pt[K_PTS];
  compute_taps(sF, fy0, fx0, gx0, gy0, xo, yo, tid, pt);

  __syncthreads();                                 // round-0 src ready

  for (int c = 0; c < 16; c += 2) {
    const float* plane0 = tgt + (size_t)c * SZ;
    eval_round(sA, sB, plane0, plane0 + SZ, pt, tid);
    __syncthreads();                               // sB (tile) ready; sA free

    if (c < 14)
      stage_pair(plane0 + 2 * SZ, plane0 + 3 * SZ, sA, xo, yo, tid);

    float acc0 = 0.0f, acc1 = 0.0f;
    #pragma unroll
    for (int dy = 0; dy < 4; ++dy) {
      float r0 = 0.0f, r1 = 0.0f;
      const int base = (2 * ly + dy) * 34 + 2 * lx;
      #pragma unroll
      for (int dx = 0; dx < 4; ++dx) {
        float2 v = sB[base + dx];
        r0 += wx[dx] * v.x;
        r1 += wx[dx] * v.y;
      }
      acc0 += wy[dy] * r0;
      acc1 += wy[dy] * r1;
    }
    size_t o = (((size_t)b * 32 + 16 + c) * HW + oy) * HW + ox;
    out[o] = acc0 * inv;
    out[o + SZ] = acc1 * inv;
    __syncthreads();                               // sA (next src) ready; sB free
  }
}

extern "C" void kernel_launch(void* const* d_in, const int* in_sizes, int n_in,
                              void* d_out, int out_size, void* d_ws, size_t ws_size,
                              hipStream_t stream) {
  const float* x   = (const float*)d_in[0];  // [2,32,512,512] f32
  const float* res = (const float*)d_in[1];  // [2,2,512,512]  f32
  const float* Wc  = (const float*)d_in[2];  // [2,50,3,3]     f32
  const float* bc  = (const float*)d_in[3];  // [2]            f32
  float* out = (float*)d_out;                // [2,32,512,512] f32

  float* adj = (float*)d_ws;                 // [2,2,512,512]

  dim3 tile_grid(32, 32, 2);

  // K1: warped_tgt -> out channels 16..31 (fp32 staging for conv)
  warp_img_kernel<<<tile_grid, dim3(256), 0, stream>>>(x, res, out);

  // K2: conv3x3 over [x(0..31) | out(16..31) | res] -> adj, plus fused src passthrough
  conv_kernel<<<tile_grid, dim3(256), 0, stream>>>(x, res, Wc, bc, out, adj);

  // K4 (fused K3+K4): hindsight warp -> out channels 16..31
  hindsight_kernel<<<tile_grid, dim3(256), 0, stream>>>(x, res, adj, out);
}

// Round 10
// 363.853 us; speedup vs baseline: 1.1585x; 1.0172x over previous
//
#include <hip/hip_runtime.h>
#include <hip/hip_bf16.h>
#include <cstdint>
#include <cstddef>

// Problem constants
#define HW   512
#define HW2  1024
#define SZ   (512 * 512)
#define NPT  (34 * 34)   // 1156 warped 1024-res points per 16x16 output tile
#define K_PTS 5          // ceil(1156 / 256)
#define SRCW 36          // staged source window: 36x36
#define NSRC (SRCW * SRCW)   // 1296
#define MARG 9           // window origin = tile_origin - MARG
#define FDIM 18          // staged field window: rows/cols [t0-1, t0+16]
#define NFLD (FDIM * FDIM)   // 324
// Fused-K4 prologue windows
#define SRCW2 38                 // res window for the nres point grid
#define NSRC2 (SRCW2 * SRCW2)    // 1444
#define MARG2 10                 // res window origin = tile_origin - MARG2
#define ADIM 20                  // adj window [t0-2, t0+17]
#define NADJ (ADIM * ADIM)       // 400

// jax.image.resize bilinear upsample 512->1024 taps for output index i (0..1023)
struct UpTap { int i0, i1; float w0, w1; };

__device__ __forceinline__ UpTap up_tap(int i) {
  UpTap t;
  int k = i >> 1;
  if ((i & 1) == 0) {
    t.i0 = k - 1; t.i1 = k; t.w0 = 0.25f; t.w1 = 0.75f;
    if (k == 0) { t.i0 = 0; t.w0 = 0.0f; t.w1 = 1.0f; }
  } else {
    t.i0 = k; t.i1 = k + 1; t.w0 = 0.75f; t.w1 = 0.25f;
    if (k == HW - 1) { t.i1 = HW - 1; t.w0 = 1.0f; t.w1 = 0.0f; }
  }
  return t;
}

// Both field components, bilinear-upsampled, from a staged LDS tile (runtime stride).
__device__ __forceinline__ float2 up_at2s(const float2* __restrict__ f,
                                          int yi, int xi, int oy, int ox, int stride) {
  UpTap ty = up_tap(yi), tx = up_tap(xi);
  const float2* r0 = f + (ty.i0 - oy) * stride - ox;
  const float2* r1 = f + (ty.i1 - oy) * stride - ox;
  float2 v00 = r0[tx.i0], v01 = r0[tx.i1];
  float2 v10 = r1[tx.i0], v11 = r1[tx.i1];
  float2 r;
  r.x = ty.w0 * (tx.w0 * v00.x + tx.w1 * v01.x) + ty.w1 * (tx.w0 * v10.x + tx.w1 * v11.x);
  r.y = ty.w0 * (tx.w0 * v00.y + tx.w1 * v01.y) + ty.w1 * (tx.w0 * v10.y + tx.w1 * v11.y);
  return r;
}

// Separable decomposition of (warp-bilinear in 1024-space) o (2x upsample):
// a 3-tap stencil on the 512 grid. Base clamped to [0,509]; out-of-range
// corners get weight 0 (zero padding, mask pre-clamp).
__device__ __forceinline__ void axis_taps(float s, int& base, float& w0, float& w1, float& w2) {
  float f0 = floorf(s);
  int i0 = (int)f0;
  float fr = s - f0;
  int b = (i0 & 1) ? (i0 >> 1) : (i0 >> 1) - 1;
  b = b < 0 ? 0 : (b > (HW - 3) ? (HW - 3) : b);
  float w[3] = {0.0f, 0.0f, 0.0f};
  if ((unsigned)i0 < (unsigned)HW2) {
    UpTap t = up_tap(i0);
    w[t.i0 - b] += (1.0f - fr) * t.w0;
    w[t.i1 - b] += (1.0f - fr) * t.w1;
  }
  if ((unsigned)(i0 + 1) < (unsigned)HW2) {
    UpTap t = up_tap(i0 + 1);
    w[t.i0 - b] += fr * t.w0;
    w[t.i1 - b] += fr * t.w1;
  }
  base = b; w0 = w[0]; w1 = w[1]; w2 = w[2];
}

// Per-point separable 3x3 stencil. locoff >= 0: index into staged 36x36 LDS window.
// locoff < 0: rare fallback, ~locoff = global by*HW+bx offset (displacement > ~8px).
struct PtTaps {
  int   locoff;
  float wy0, wy1, wy2, wx0, wx1, wx2;
};

// Stage the 18x18 field window (fx,fy interleaved) into LDS.
__device__ __forceinline__ void stage_field(const float* __restrict__ fx,
                                            const float* __restrict__ fy,
                                            float2* __restrict__ sf,
                                            int fy0, int fx0, int tid) {
  #pragma unroll
  for (int i = 0; i < 2; ++i) {
    int p = tid + i * 256;
    if (p < NFLD) {
      int r = p / FDIM, c = p % FDIM;
      int gy = fy0 + r; gy = gy < 0 ? 0 : (gy > HW - 1 ? HW - 1 : gy);
      int gx = fx0 + c; gx = gx < 0 ? 0 : (gx > HW - 1 ? HW - 1 : gx);
      size_t o = (size_t)gy * HW + gx;
      sf[p] = make_float2(fx[o], fy[o]);
    }
  }
}

// Taps from an LDS-staged 18x18 field (no global loads).
__device__ __forceinline__ void compute_taps(const float2* __restrict__ sf,
                                             int fy0, int fx0,
                                             int gx0, int gy0, int xo, int yo, int tid,
                                             PtTaps (&pt)[K_PTS]) {
  #pragma unroll
  for (int i = 0; i < K_PTS; ++i) {
    int p = tid + i * 256;
    pt[i].locoff = 0;
    pt[i].wy0 = pt[i].wy1 = pt[i].wy2 = 0.0f;
    pt[i].wx0 = pt[i].wx1 = pt[i].wx2 = 0.0f;
    if (p < NPT) {
      int ry = p / 34, rx = p % 34;
      int yy = gy0 + ry, xx = gx0 + rx;
      if ((unsigned)yy < (unsigned)HW2 && (unsigned)xx < (unsigned)HW2) {
        float2 d = up_at2s(sf, yy, xx, fy0, fx0, FDIM);
        float sx = (float)xx + 2.0f * d.x;
        float sy = (float)yy + 2.0f * d.y;
        int bx, by;
        axis_taps(sx, bx, pt[i].wx0, pt[i].wx1, pt[i].wx2);
        axis_taps(sy, by, pt[i].wy0, pt[i].wy1, pt[i].wy2);
        int rx_ = bx - xo, ry_ = by - yo;
        if ((unsigned)rx_ <= (unsigned)(SRCW - 3) && (unsigned)ry_ <= (unsigned)(SRCW - 3))
          pt[i].locoff = ry_ * SRCW + rx_;          // in staged window
        else
          pt[i].locoff = ~(by * HW + bx);           // fallback: global offset
      }
    }
  }
}

// Stage a channel pair's 36x36 source window into LDS (float2 interleaved).
__device__ __forceinline__ void stage_pair(const float* __restrict__ p0,
                                           const float* __restrict__ p1,
                                           float2* __restrict__ s_src,
                                           int xo, int yo, int tid) {
  #pragma unroll
  for (int i = 0; i < 6; ++i) {                   // 6*256 = 1536 >= 1296
    int p = tid + i * 256;
    if (p < NSRC) {
      int r = p / SRCW, c = p % SRCW;
      int gy = yo + r; gy = gy < 0 ? 0 : (gy > HW - 1 ? HW - 1 : gy);
      int gx = xo + c; gx = gx < 0 ? 0 : (gx > HW - 1 ? HW - 1 : gx);
      size_t o = (size_t)gy * HW + gx;
      s_src[p] = make_float2(p0[o], p1[o]);
    }
  }
}

__device__ __forceinline__ float eval3_global(const float* __restrict__ pl, int off, const PtTaps& t) {
  const float* p0 = pl + off;
  float r0 = t.wx0 * p0[0]        + t.wx1 * p0[1]          + t.wx2 * p0[2];
  float r1 = t.wx0 * p0[HW]       + t.wx1 * p0[HW + 1]     + t.wx2 * p0[HW + 2];
  float r2 = t.wx0 * p0[2 * HW]   + t.wx1 * p0[2 * HW + 1] + t.wx2 * p0[2 * HW + 2];
  return t.wy0 * r0 + t.wy1 * r1 + t.wy2 * r2;
}

// Evaluate all points of a channel pair from the staged LDS window into s_tile.
__device__ __forceinline__ void eval_round(const float2* __restrict__ s_src,
                                           float2* __restrict__ s_tile,
                                           const float* __restrict__ plane0,
                                           const float* __restrict__ plane1,
                                           const PtTaps (&pt)[K_PTS], int tid) {
  #pragma unroll
  for (int i = 0; i < K_PTS; ++i) {
    int p = tid + i * 256;
    if (p < NPT) {
      const PtTaps t = pt[i];
      float a0, a1;
      if (t.locoff >= 0) {
        const float2* s = s_src + t.locoff;
        float2 v00 = s[0],        v01 = s[1],            v02 = s[2];
        float2 v10 = s[SRCW],     v11 = s[SRCW + 1],     v12 = s[SRCW + 2];
        float2 v20 = s[2 * SRCW], v21 = s[2 * SRCW + 1], v22 = s[2 * SRCW + 2];
        float r00 = t.wx0 * v00.x + t.wx1 * v01.x + t.wx2 * v02.x;
        float r10 = t.wx0 * v10.x + t.wx1 * v11.x + t.wx2 * v12.x;
        float r20 = t.wx0 * v20.x + t.wx1 * v21.x + t.wx2 * v22.x;
        float r01 = t.wx0 * v00.y + t.wx1 * v01.y + t.wx2 * v02.y;
        float r11 = t.wx0 * v10.y + t.wx1 * v11.y + t.wx2 * v12.y;
        float r21 = t.wx0 * v20.y + t.wx1 * v21.y + t.wx2 * v22.y;
        a0 = t.wy0 * r00 + t.wy1 * r10 + t.wy2 * r20;
        a1 = t.wy0 * r01 + t.wy1 * r11 + t.wy2 * r21;
      } else {                                     // ~never taken (|disp| > ~8px)
        int off = ~t.locoff;
        a0 = eval3_global(plane0, off, t);
        a1 = eval3_global(plane1, off, t);
      }
      s_tile[p] = make_float2(a0, a1);
    }
  }
}

// -------------------- K1: res_warp_img(tgt, res, rollback=1) --------------------
// Round-1 structure (VGPR=64 invariant) + LDS-staged warp field for the tap phase.
__global__ void warp_img_kernel(const float* __restrict__ x,    // [B,32,512,512]
                                const float* __restrict__ res,  // [B,2,512,512]
                                float* __restrict__ out)        // [B,32,512,512]
{
  __shared__ float2 s_src[NSRC];   // 10368 B
  __shared__ float2 s_tile[NPT];   //  9248 B  (prologue: holds the 18x18 field tile)

  const int b = blockIdx.z;
  const int tx0 = blockIdx.x * 16, ty0 = blockIdx.y * 16;
  const int gx0 = tx0 * 2 - 1, gy0 = ty0 * 2 - 1;
  const int xo = tx0 - MARG, yo = ty0 - MARG;
  const int fy0 = ty0 - 1, fx0 = tx0 - 1;
  const int tid = threadIdx.x;

  const float* resx = res + (size_t)b * 2 * SZ;
  const float* resy = resx + SZ;
  const float* tgt  = x + ((size_t)b * 32 + 16) * SZ;

  // Issue round-0 channel staging + field staging together.
  stage_pair(tgt, tgt + SZ, s_src, xo, yo, tid);
  stage_field(resx, resy, s_tile, fy0, fx0, tid);

  // Downsample stencil weights for this thread's output pixel
  const int ly = tid >> 4, lx = tid & 15;
  const int oy = ty0 + ly, ox = tx0 + lx;
  const float RW[4] = {0.25f, 0.75f, 0.75f, 0.25f};
  float wy[4], wx[4];
  float sumy = 0.f, sumx = 0.f;
  #pragma unroll
  for (int d = 0; d < 4; ++d) {
    int g = 2 * oy - 1 + d;
    wy[d] = ((unsigned)g < (unsigned)HW2) ? RW[d] : 0.0f; sumy += wy[d];
    g = 2 * ox - 1 + d;
    wx[d] = ((unsigned)g < (unsigned)HW2) ? RW[d] : 0.0f; sumx += wx[d];
  }
  const float inv = 1.0f / (sumy * sumx);

  __syncthreads();                                 // field + round-0 src ready

  PtTaps pt[K_PTS];
  compute_taps(s_tile, fy0, fx0, gx0, gy0, xo, yo, tid, pt);

  __syncthreads();                                 // field reads done; s_tile free

  for (int c = 0; c < 16; c += 2) {
    const float* plane0 = tgt + (size_t)c * SZ;
    eval_round(s_src, s_tile, plane0, plane0 + SZ, pt, tid);
    __syncthreads();                               // s_tile ready; s_src free

    if (c < 14)                                    // overlap next staging with phase 3
      stage_pair(plane0 + 2 * SZ, plane0 + 3 * SZ, s_src, xo, yo, tid);

    float acc0 = 0.0f, acc1 = 0.0f;
    #pragma unroll
    for (int dy = 0; dy < 4; ++dy) {
      float r0 = 0.0f, r1 = 0.0f;
      const int base = (2 * ly + dy) * 34 + 2 * lx;
      #pragma unroll
      for (int dx = 0; dx < 4; ++dx) {
        float2 v = s_tile[base + dx];
        r0 += wx[dx] * v.x;
        r1 += wx[dx] * v.y;
      }
      acc0 += wy[dy] * r0;
      acc1 += wy[dy] * r1;
    }
    size_t o = (((size_t)b * 32 + 16 + c) * HW + oy) * HW + ox;
    out[o] = acc0 * inv;
    out[o + SZ] = acc1 * inv;
    __syncthreads();                               // s_src(next) ready; s_tile free
  }
}

// -------------------- K2: 3x3 conv over 50-ch bundle -> 2-ch adj --------------------
// Round-8 quad structure + ONE change: halo LDS is plane-PAIR interleaved float2.
// 9 ds_read_b64 per plane-pair replaces 18 ds_read_b32 -> halo LDS read
// instructions halve (450->225), cycles -37%. Scalar staging loads (VGPR-cheap,
// round-5-proven), T14 write-late, global-weight s_load path, fused passthrough.
#define CHN 18                     // halo width (16 + 2)
#define CHE (CHN * CHN)            // 324 elements

__global__ void __launch_bounds__(256)
conv_kernel(const float* __restrict__ x,
            const float* __restrict__ res,
            const float* __restrict__ Wc,      // [2,50,3,3]
            const float* __restrict__ bc,      // [2]
            float* __restrict__ out,           // [B,32,512,512]: reads ch16..31 (warped), writes ch0..15
            float* __restrict__ adj)           // [B,2,512,512]
{
  __shared__ float2 sh[4][CHE];    // [quadbuf(2)][pair(2)]: 10368 B

  const int tid = threadIdx.x;
  const int b = blockIdx.z;
  const int tx0 = blockIdx.x * 16, ty0 = blockIdx.y * 16;
  const int ty = tid >> 4, tx = tid & 15;

  const float* px = x + (size_t)b * 32 * SZ;
  const float* pw = out + ((size_t)b * 32 + 16) * SZ;
  const float* pr = res + (size_t)b * 2 * SZ;

  const int ry0 = tid / CHN, rx0 = tid - ry0 * CHN;
  const int hy0 = ty0 - 1 + ry0, hx0 = tx0 - 1 + rx0;
  const bool ok0 = (unsigned)hy0 < (unsigned)HW && (unsigned)hx0 < (unsigned)HW;
  const int off0 = hy0 * HW + hx0;
  const int p1 = tid + 256;
  const bool sl1 = p1 < CHE;
  const int ry1 = p1 / CHN, rx1 = p1 - ry1 * CHN;
  const int hy1 = ty0 - 1 + ry1, hx1 = tx0 - 1 + rx1;
  const bool ok1 = sl1 && (unsigned)hy1 < (unsigned)HW && (unsigned)hx1 < (unsigned)HW;
  const int off1 = hy1 * HW + hx1;

  #define PLANE(ic) ((ic) < 32 ? px + (size_t)(ic) * SZ \
                   : (ic) < 48 ? pw + (size_t)((ic) - 32) * SZ \
                   : pr + (size_t)((ic) - 48) * SZ)

  float acc0 = bc[0];
  float acc1 = bc[1];

  float q0[4], q1[4];
  {  // prologue: stage quad 0 (planes 0..3) into sh[0],sh[1]
    #pragma unroll
    for (int j = 0; j < 4; ++j) {
      const float* pl = PLANE(j);
      q0[j] = ok0 ? pl[off0] : 0.f;
      q1[j] = ok1 ? pl[off1] : 0.f;
    }
    sh[0][tid] = make_float2(q0[0], q0[1]);
    sh[1][tid] = make_float2(q0[2], q0[3]);
    if (sl1) {
      sh[0][p1] = make_float2(q1[0], q1[1]);
      sh[1][p1] = make_float2(q1[2], q1[3]);
    }
  }

  const size_t pix = (size_t)(ty0 + ty) * HW + (tx0 + tx);

  for (int kk = 0; kk < 12; ++kk) {
    __syncthreads();                      // current quad ready; other buffer free
    if (kk < 11) {                        // issue next quad's loads before compute (T14)
      #pragma unroll
      for (int j = 0; j < 4; ++j) {
        const float* pl = PLANE(4 * kk + 4 + j);
        q0[j] = ok0 ? pl[off0] : 0.f;
        q1[j] = ok1 ? pl[off1] : 0.f;
      }
    } else {                              // last: stage the res pair (ch 48,49)
      #pragma unroll
      for (int j = 0; j < 2; ++j) {
        const float* pl = PLANE(48 + j);
        q0[j] = ok0 ? pl[off0] : 0.f;
        q1[j] = ok1 ? pl[off1] : 0.f;
      }
    }

    const int cur = (kk & 1) * 2;
    const float* w0 = Wc + (size_t)(4 * kk) * 9;        // uniform index -> s_load
    const float* w1 = Wc + 450 + (size_t)(4 * kk) * 9;
    float2 cenA, cenB;
    #pragma unroll
    for (int ky = 0; ky < 3; ++ky) {
      #pragma unroll
      for (int kx = 0; kx < 3; ++kx) {
        const int hoff = (ty + ky) * CHN + tx + kx;
        const int widx = ky * 3 + kx;
        float2 vA = sh[cur][hoff];        // planes 4kk, 4kk+1
        float2 vB = sh[cur + 1][hoff];    // planes 4kk+2, 4kk+3
        if (ky == 1 && kx == 1) { cenA = vA; cenB = vB; }
        acc0 += vA.x * w0[widx];
        acc0 += vA.y * w0[9 + widx];
        acc0 += vB.x * w0[18 + widx];
        acc0 += vB.y * w0[27 + widx];
        acc1 += vA.x * w1[widx];
        acc1 += vA.y * w1[9 + widx];
        acc1 += vB.x * w1[18 + widx];
        acc1 += vB.y * w1[27 + widx];
      }
    }

    if (kk < 4) {                         // fused K0: out ch 4kk..4kk+3 = x ch 4kk..4kk+3
      out[((size_t)b * 32 + 4 * kk + 0) * SZ + pix] = cenA.x;
      out[((size_t)b * 32 + 4 * kk + 1) * SZ + pix] = cenA.y;
      out[((size_t)b * 32 + 4 * kk + 2) * SZ + pix] = cenB.x;
      out[((size_t)b * 32 + 4 * kk + 3) * SZ + pix] = cenB.y;
    }

    const int nxt = cur ^ 2;              // write-late into the other quad-buffer
    if (kk < 11) {
      sh[nxt][tid] = make_float2(q0[0], q0[1]);
      sh[nxt + 1][tid] = make_float2(q0[2], q0[3]);
      if (sl1) {
        sh[nxt][p1] = make_float2(q1[0], q1[1]);
        sh[nxt + 1][p1] = make_float2(q1[2], q1[3]);
      }
    } else {
      sh[nxt][tid] = make_float2(q0[0], q0[1]);
      if (sl1) sh[nxt][p1] = make_float2(q1[0], q1[1]);
    }
  }

  // epilogue: res pair (ch 48,49) sits in sh[0] (kk=11 wrote nxt = 0)
  __syncthreads();
  {
    const float* w0 = Wc + (size_t)48 * 9;
    const float* w1 = Wc + 450 + (size_t)48 * 9;
    #pragma unroll
    for (int ky = 0; ky < 3; ++ky) {
      #pragma unroll
      for (int kx = 0; kx < 3; ++kx) {
        const int hoff = (ty + ky) * CHN + tx + kx;
        const int widx = ky * 3 + kx;
        float2 v = sh[0][hoff];
        acc0 += v.x * w0[widx];
        acc0 += v.y * w0[9 + widx];
        acc1 += v.x * w1[widx];
        acc1 += v.y * w1[9 + widx];
      }
    }
  }
  #undef PLANE

  adj[((size_t)b * 2 + 0) * SZ + pix] = acc0;
  adj[((size_t)b * 2 + 1) * SZ + pix] = acc1;
}

// -------------------- K4 (fused K3+K4): hindsight warp --------------------
// Prologue computes this tile's 18x18 nres field window entirely in LDS
// (replicating new_res_kernel's arithmetic), then runs the standard warp.
__global__ void hindsight_kernel(const float* __restrict__ x,    // [B,32,512,512]
                                 const float* __restrict__ res,  // [B,2,512,512]
                                 const float* __restrict__ adj,  // [B,2,512,512]
                                 float* __restrict__ out)        // [B,32,512,512]
{
  __shared__ float2 sA[NSRC2];  // P1: nres point grid (1444) | main: s_src (1296)
  __shared__ float2 sB[NSRC2];  // P0: res 38x38 window      | main: s_tile (1156)
  __shared__ float2 sC[NADJ];   // adj 20x20 window
  __shared__ float2 sF[NFLD];   // 18x18 nres field tile (lives whole kernel)

  const int b = blockIdx.z;
  const int tx0 = blockIdx.x * 16, ty0 = blockIdx.y * 16;
  const int gx0 = tx0 * 2 - 1, gy0 = ty0 * 2 - 1;
  const int xo = tx0 - MARG, yo = ty0 - MARG;
  const int fy0 = ty0 - 1, fx0 = tx0 - 1;
  const int yo2 = ty0 - MARG2, xo2 = tx0 - MARG2;
  const int tid = threadIdx.x;

  const float* adjx = adj + (size_t)b * 2 * SZ;
  const float* adjy = adjx + SZ;
  const float* res0 = res + (size_t)b * 2 * SZ;
  const float* res1 = res0 + SZ;
  const float* tgt  = x + ((size_t)b * 32 + 16) * SZ;

  // ---- P0: stage res 38x38 -> sB, adj 20x20 -> sC
  #pragma unroll
  for (int i = 0; i < 6; ++i) {
    int p = tid + i * 256;
    if (p < NSRC2) {
      int r = p / SRCW2, c = p % SRCW2;
      int gy = yo2 + r; gy = gy < 0 ? 0 : (gy > HW - 1 ? HW - 1 : gy);
      int gx = xo2 + c; gx = gx < 0 ? 0 : (gx > HW - 1 ? HW - 1 : gx);
      size_t o = (size_t)gy * HW + gx;
      sB[p] = make_float2(res0[o], res1[o]);
    }
  }
  #pragma unroll
  for (int i = 0; i < 2; ++i) {
    int p = tid + i * 256;
    if (p < NADJ) {
      int r = p / ADIM, c = p % ADIM;
      int gy = ty0 - 2 + r; gy = gy < 0 ? 0 : (gy > HW - 1 ? HW - 1 : gy);
      int gx = tx0 - 2 + c; gx = gx < 0 ? 0 : (gx > HW - 1 ? HW - 1 : gx);
      size_t o = (size_t)gy * HW + gx;
      sC[p] = make_float2(adjx[o], adjy[o]);
    }
  }

  // Downsample stencil weights for this thread's output pixel (main phase)
  const int ly = tid >> 4, lx = tid & 15;
  const int oy = ty0 + ly, ox = tx0 + lx;
  const float RW[4] = {0.25f, 0.75f, 0.75f, 0.25f};
  float wy[4], wx[4];
  float sumy = 0.f, sumx = 0.f;
  #pragma unroll
  for (int d = 0; d < 4; ++d) {
    int g = 2 * oy - 1 + d;
    wy[d] = ((unsigned)g < (unsigned)HW2) ? RW[d] : 0.0f; sumy += wy[d];
    g = 2 * ox - 1 + d;
    wx[d] = ((unsigned)g < (unsigned)HW2) ? RW[d] : 0.0f; sumx += wx[d];
  }
  const float inv = 1.0f / (sumy * sumx);

  __syncthreads();                                 // sB, sC ready

  // ---- P1: evaluate the 38x38 nres point grid -> sA
  {
    const int qy0 = 2 * fy0 - 1, qx0 = 2 * fx0 - 1;
    #pragma unroll
    for (int i = 0; i < 6; ++i) {
      int p = tid + i * 256;
      if (p < NSRC2) {
        int r = p / SRCW2, c = p % SRCW2;
        int qy = qy0 + r, qx = qx0 + c;
        float a0 = 0.f, a1 = 0.f;
        if ((unsigned)qy < (unsigned)HW2 && (unsigned)qx < (unsigned)HW2) {
          float2 d = up_at2s(sC, qy, qx, ty0 - 2, tx0 - 2, ADIM);
          float sxx = (float)qx + 2.0f * d.x;
          float syy = (float)qy + 2.0f * d.y;
          PtTaps t;
          int bx, by;
          axis_taps(sxx, bx, t.wx0, t.wx1, t.wx2);
          axis_taps(syy, by, t.wy0, t.wy1, t.wy2);
          int rx_ = bx - xo2, ry_ = by - yo2;
          if ((unsigned)rx_ <= (unsigned)(SRCW2 - 3) && (unsigned)ry_ <= (unsigned)(SRCW2 - 3)) {
            const float2* s = sB + ry_ * SRCW2 + rx_;
            float2 v00 = s[0],         v01 = s[1],             v02 = s[2];
            float2 v10 = s[SRCW2],     v11 = s[SRCW2 + 1],     v12 = s[SRCW2 + 2];
            float2 v20 = s[2 * SRCW2], v21 = s[2 * SRCW2 + 1], v22 = s[2 * SRCW2 + 2];
            float r00 = t.wx0 * v00.x + t.wx1 * v01.x + t.wx2 * v02.x;
            float r10 = t.wx0 * v10.x + t.wx1 * v11.x + t.wx2 * v12.x;
            float r20 = t.wx0 * v20.x + t.wx1 * v21.x + t.wx2 * v22.x;
            float r01 = t.wx0 * v00.y + t.wx1 * v01.y + t.wx2 * v02.y;
            float r11 = t.wx0 * v10.y + t.wx1 * v11.y + t.wx2 * v12.y;
            float r21 = t.wx0 * v20.y + t.wx1 * v21.y + t.wx2 * v22.y;
            a0 = t.wy0 * r00 + t.wy1 * r10 + t.wy2 * r20;
            a1 = t.wy0 * r01 + t.wy1 * r11 + t.wy2 * r21;
          } else {                                 // ~never taken
            int off = by * HW + bx;
            a0 = eval3_global(res0, off, t);
            a1 = eval3_global(res1, off, t);
          }
        }
        sA[p] = make_float2(a0, a1);
      }
    }
  }
  __syncthreads();                                 // sA (point grid) ready

  // ---- P2: downsample + adj-center add -> sF (18x18 nres tile)
  #pragma unroll
  for (int i = 0; i < 2; ++i) {
    int p = tid + i * 256;
    if (p < NFLD) {
      int pr = p / FDIM, pc = p % FDIM;
      int py = fy0 + pr; py = py < 0 ? 0 : (py > HW - 1 ? HW - 1 : py);
      int px = fx0 + pc; px = px < 0 ? 0 : (px > HW - 1 ? HW - 1 : px);
      float wyv[4], wxv[4];
      float sy = 0.f, sx = 0.f;
      #pragma unroll
      for (int d = 0; d < 4; ++d) {
        int g = 2 * py - 1 + d;
        wyv[d] = ((unsigned)g < (unsigned)HW2) ? RW[d] : 0.0f; sy += wyv[d];
        g = 2 * px - 1 + d;
        wxv[d] = ((unsigned)g < (unsigned)HW2) ? RW[d] : 0.0f; sx += wxv[d];
      }
      float inv2 = 1.0f / (sy * sx);
      float a0 = 0.f, a1 = 0.f;
      #pragma unroll
      for (int dy = 0; dy < 4; ++dy) {
        float r0 = 0.f, r1 = 0.f;
        const int base = (2 * (py - fy0) + dy) * SRCW2 + 2 * (px - fx0);
        #pragma unroll
        for (int dx = 0; dx < 4; ++dx) {
          float2 v = sA[base + dx];
          r0 += wxv[dx] * v.x;
          r1 += wxv[dx] * v.y;
        }
        a0 += wyv[dy] * r0;
        a1 += wyv[dy] * r1;
      }
      float2 ac = sC[(py - (ty0 - 2)) * ADIM + (px - (tx0 - 2))];
      sF[p] = make_float2(a0 * inv2 + ac.x, a1 * inv2 + ac.y);
    }
  }
  __syncthreads();                                 // sF ready; sA, sB free

  // ---- main warp phase (identical to warp_img_kernel, field = sF)
  stage_pair(tgt, tgt + SZ, sA, xo, yo, tid);      // round-0 channel staging

  PtTaps pt[K_PTS];
  compute_taps(sF, fy0, fx0, gx0, gy0, xo, yo, tid, pt);

  __syncthreads();                                 // round-0 src ready

  for (int c = 0; c < 16; c += 2) {
    const float* plane0 = tgt + (size_t)c * SZ;
    eval_round(sA, sB, plane0, plane0 + SZ, pt, tid);
    __syncthreads();                               // sB (tile) ready; sA free

    if (c < 14)
      stage_pair(plane0 + 2 * SZ, plane0 + 3 * SZ, sA, xo, yo, tid);

    float acc0 = 0.0f, acc1 = 0.0f;
    #pragma unroll
    for (int dy = 0; dy < 4; ++dy) {
      float r0 = 0.0f, r1 = 0.0f;
      const int base = (2 * ly + dy) * 34 + 2 * lx;
      #pragma unroll
      for (int dx = 0; dx < 4; ++dx) {
        float2 v = sB[base + dx];
        r0 += wx[dx] * v.x;
        r1 += wx[dx] * v.y;
      }
      acc0 += wy[dy] * r0;
      acc1 += wy[dy] * r1;
    }
    size_t o = (((size_t)b * 32 + 16 + c) * HW + oy) * HW + ox;
    out[o] = acc0 * inv;
    out[o + SZ] = acc1 * inv;
    __syncthreads();                               // sA (next src) ready; sB free
  }
}

extern "C" void kernel_launch(void* const* d_in, const int* in_sizes, int n_in,
                              void* d_out, int out_size, void* d_ws, size_t ws_size,
                              hipStream_t stream) {
  const float* x   = (const float*)d_in[0];  // [2,32,512,512] f32
  const float* res = (const float*)d_in[1];  // [2,2,512,512]  f32
  const float* Wc  = (const float*)d_in[2];  // [2,50,3,3]     f32
  const float* bc  = (const float*)d_in[3];  // [2]            f32
  float* out = (float*)d_out;                // [2,32,512,512] f32

  float* adj = (float*)d_ws;                 // [2,2,512,512]

  dim3 tile_grid(32, 32, 2);

  // K1: warped_tgt -> out channels 16..31 (fp32 staging for conv)
  warp_img_kernel<<<tile_grid, dim3(256), 0, stream>>>(x, res, out);

  // K2: conv3x3 over [x(0..31) | out(16..31) | res] -> adj, plus fused src passthrough
  conv_kernel<<<tile_grid, dim3(256), 0, stream>>>(x, res, Wc, bc, out, adj);

  // K4 (fused K3+K4): hindsight warp -> out channels 16..31
  hindsight_kernel<<<tile_grid, dim3(256), 0, stream>>>(x, res, adj, out);
}